// Round 6
// baseline (849.172 us; speedup 1.0000x reference)
//
#include <hip/hip_runtime.h>
#include <math.h>

#define CNW 9216000      // C*N*W = 96*1000*96
#define TOT 18432000     // B*C*N*W
#define EPSV 1e-5f
#define ITEMP 0.10206207261596575f   // 1/sqrt(96)

// ---------------- conv1x1 with optional fused pre/post transforms -----------
// MODE 0: plain conv (+bias)
// MODE 1: GN-fold — weights scaled by per-(b,c) GN scale; GN shift folded into
//         bias via u-trick: out = W'@a + (bias + W'@u), u = sh/scv. st_in=stGN.
// MODE 2: input transform x' = relu(x*scl[b,c]+shf[b,c]) (BN1(IN) fold). st_in=stIN1.
// STATS 0: none; 1: atomicAdd per-channel sums to st_out[o*2..]; 2: per-(b,o).
template <int MODE, int STATS>
__global__ __launch_bounds__(256) void conv_k(const float* __restrict__ x,
    const float* __restrict__ w, const float* __restrict__ bias,
    float* __restrict__ out, const float* __restrict__ st_in,
    const float* __restrict__ aw, const float* __restrict__ ab,
    float* __restrict__ st_out) {
  __shared__ float xt[96 * 100];
  __shared__ float wt[96 * 100];
  __shared__ float scl[96], shf[96], bias2[96];
  __shared__ float red[192];
  int b = blockIdx.x / 1000, n = blockIdx.x % 1000;
  int t = threadIdx.x;
  if (STATS && t < 192) red[t] = 0.f;
  if (MODE == 1) {
    if (t < 96) {
      int g = t >> 4;
      float m = st_in[(b * 6 + g) * 2] * (1.f / 1536000.f);
      float v = st_in[(b * 6 + g) * 2 + 1] * (1.f / 1536000.f) - m * m;
      float sc = rsqrtf(v + EPSV) * aw[t];
      float sh = ab[t] - m * sc;
      scl[t] = sc;
      shf[t] = sh / sc;          // u[c]
    }
    __syncthreads();
  } else if (MODE == 2) {
    if (t < 96) {
      const float inv = 1.f / 96000.f;
      float m0 = st_in[t * 2] * inv, v0 = st_in[t * 2 + 1] * inv - m0 * m0;
      float m1 = st_in[(96 + t) * 2] * inv, v1 = st_in[(96 + t) * 2 + 1] * inv - m1 * m1;
      float bv = 0.5f * (v0 / (v0 + EPSV) + v1 / (v1 + EPSV));
      float bscale = rsqrtf(bv + EPSV) * aw[t];
      float mi = b ? m1 : m0, vi = b ? v1 : v0;
      float sc = rsqrtf(vi + EPSV) * bscale;
      scl[t] = sc;
      shf[t] = ab[t] - mi * sc;
    }
    __syncthreads();
  }
  const float* xp = x + b * CNW + n * 96;
  for (int i = t; i < 9216; i += 256) {
    int cc = i / 96, j = i % 96;
    float xv = xp[cc * 96000 + j];
    if (MODE == 2) xv = fmaxf(xv * scl[cc] + shf[cc], 0.f);
    xt[cc * 100 + j] = xv;
    float wv = w[i];               // i = o*96 + c : o=cc, c=j
    if (MODE == 1) wv *= scl[j];
    wt[cc * 100 + j] = wv;
  }
  __syncthreads();
  // idle threads compute the folded bias for MODE 1 (concurrent with compute)
  if (MODE == 1 && t >= 192) {
    for (int o = t - 192; o < 96; o += 64) {
      float acc = bias ? bias[o] : 0.f;
      for (int c2 = 0; c2 < 96; ++c2) acc += wt[o * 100 + c2] * shf[c2];
      bias2[o] = acc;
    }
  }
  float4 acc[12];
#pragma unroll
  for (int oo = 0; oo < 12; ++oo) acc[oo] = make_float4(0.f, 0.f, 0.f, 0.f);
  int wq = t % 24, og = t / 24;       // w = 4*wq+r, o = og*12+oo
  if (t < 192) {
    for (int cq = 0; cq < 24; ++cq) {
      float4 xv0 = *(const float4*)&xt[(4 * cq + 0) * 100 + 4 * wq];
      float4 xv1 = *(const float4*)&xt[(4 * cq + 1) * 100 + 4 * wq];
      float4 xv2 = *(const float4*)&xt[(4 * cq + 2) * 100 + 4 * wq];
      float4 xv3 = *(const float4*)&xt[(4 * cq + 3) * 100 + 4 * wq];
#pragma unroll
      for (int oo = 0; oo < 12; ++oo) {
        int o = og * 12 + oo;
        float4 wv = *(const float4*)&wt[o * 100 + 4 * cq];
        acc[oo].x += wv.x * xv0.x + wv.y * xv1.x + wv.z * xv2.x + wv.w * xv3.x;
        acc[oo].y += wv.x * xv0.y + wv.y * xv1.y + wv.z * xv2.y + wv.w * xv3.y;
        acc[oo].z += wv.x * xv0.z + wv.y * xv1.z + wv.z * xv2.z + wv.w * xv3.z;
        acc[oo].w += wv.x * xv0.w + wv.y * xv1.w + wv.z * xv2.w + wv.w * xv3.w;
      }
    }
  }
  __syncthreads();     // bias2 ready; red zeroed
  if (t < 192) {
    float* op = out + b * CNW + n * 96 + 4 * wq;
#pragma unroll
    for (int oo = 0; oo < 12; ++oo) {
      int o = og * 12 + oo;
      float4 v = acc[oo];
      float bb = (MODE == 1) ? bias2[o] : (bias ? bias[o] : 0.f);
      v.x += bb; v.y += bb; v.z += bb; v.w += bb;
      *(float4*)&op[o * 96000] = v;
      if (STATS) {
        float s = v.x + v.y + v.z + v.w;
        float q = v.x * v.x + v.y * v.y + v.z * v.z + v.w * v.w;
        atomicAdd(&red[o * 2 + 0], s);
        atomicAdd(&red[o * 2 + 1], q);
      }
    }
  }
  if (STATS) {
    __syncthreads();
    if (t < 192) {
      int base = (STATS == 2) ? b * 192 : 0;
      atomicAdd(&st_out[base + t], red[t]);
    }
  }
}

// ---------------- attention kernel A: block means -> sinkhorn -> top3 cut -> P
__global__ __launch_bounds__(256) void attnA_k(const float* __restrict__ feat,
                                               float* __restrict__ Pg) {
  int head = blockIdx.x;
  int b = head / 576, rem = head % 576, c = rem / 6, gr = rem % 6;
  const float* fb = feat + b * CNW + c * 96000 + gr * 16;
  __shared__ float qm[160];     // [10][16]
  __shared__ float L[110];      // [10][11]
  int t = threadIdx.x;
  if (t < 160) {
    int m = t / 16, j = t % 16;
    float s = 0.f;
    for (int ss = 0; ss < 100; ++ss) s += fb[(m * 100 + ss) * 96 + j];
    qm[m * 16 + j] = s * 0.01f;
  }
  __syncthreads();
  if (t < 100) {
    int m = t / 10, n2 = t % 10;
    float acc = 0.f;
#pragma unroll
    for (int j = 0; j < 16; ++j) acc += qm[m * 16 + j] * qm[n2 * 16 + j];
    L[m * 11 + n2] = acc * ITEMP;
  }
  __syncthreads();
  for (int it = 0; it < 8; ++it) {
    if (t < 10) {   // row LSE (axis=-1)
      float mx = -3.4e38f;
      for (int n2 = 0; n2 < 10; ++n2) mx = fmaxf(mx, L[t * 11 + n2]);
      float s = 0.f;
      for (int n2 = 0; n2 < 10; ++n2) s += expf(L[t * 11 + n2] - mx);
      float lse = mx + logf(s);
      for (int n2 = 0; n2 < 10; ++n2) L[t * 11 + n2] -= lse;
    }
    __syncthreads();
    if (t < 10) {   // col LSE (axis=-2)
      float mx = -3.4e38f;
      for (int m = 0; m < 10; ++m) mx = fmaxf(mx, L[m * 11 + t]);
      float s = 0.f;
      for (int m = 0; m < 10; ++m) s += expf(L[m * 11 + t] - mx);
      float lse = mx + logf(s);
      for (int m = 0; m < 10; ++m) L[m * 11 + t] -= lse;
    }
    __syncthreads();
  }
  if (t < 10) {
    float p[10];
#pragma unroll
    for (int n2 = 0; n2 < 10; ++n2) p[n2] = expf(L[t * 11 + n2]);
    int i1 = -1, i2 = -1;
    float m1 = -1.f, m2 = -1.f, m3 = -1.f;
#pragma unroll
    for (int n2 = 0; n2 < 10; ++n2) if (p[n2] > m1) { m1 = p[n2]; i1 = n2; }
#pragma unroll
    for (int n2 = 0; n2 < 10; ++n2) if (n2 != i1 && p[n2] > m2) { m2 = p[n2]; i2 = n2; }
#pragma unroll
    for (int n2 = 0; n2 < 10; ++n2) if (n2 != i1 && n2 != i2 && p[n2] > m3) m3 = p[n2];
#pragma unroll
    for (int n2 = 0; n2 < 10; ++n2)
      Pg[head * 100 + t * 10 + n2] = (p[n2] >= m3) ? p[n2] : 0.f;
  }
}

// ---------------- attention kernel B (flash-style, ILP-2 over keys) ---------
// grid decoded as m = bid/1152, head = bid%1152 so the 10 m-blocks of a head
// share an XCD (1152 % 8 == 0) -> L2 reuse of the head's feat tile.
__global__ __launch_bounds__(128) void attnB_k(const float* __restrict__ feat,
    const float* __restrict__ Pg, float* __restrict__ out) {
  int m = blockIdx.x / 1152;
  int head = blockIdx.x % 1152;
  int b = head / 576, rem = head % 576, c = rem / 6, gr = rem % 6;
  const float* fb = feat + b * CNW + c * 96000 + gr * 16;
  __shared__ float sk[100 * 16];
  __shared__ float sv[100 * 16];
  int t = threadIdx.x;
  float p[10];
#pragma unroll
  for (int n2 = 0; n2 < 10; ++n2) p[n2] = Pg[head * 100 + m * 10 + n2];
  // build mixed sk/sv (v = elu(k), branchless)
  for (int i4 = t; i4 < 400; i4 += 128) {
    int s = i4 >> 2, q = i4 & 3;
    float4 ak = make_float4(0.f, 0.f, 0.f, 0.f);
    float4 av = make_float4(0.f, 0.f, 0.f, 0.f);
#pragma unroll
    for (int n2 = 0; n2 < 10; ++n2) {
      if (p[n2] != 0.f) {
        float4 kv = *(const float4*)&fb[(n2 * 100 + s) * 96 + 4 * q];
        float pe = p[n2];
        ak.x += pe * kv.x; ak.y += pe * kv.y; ak.z += pe * kv.z; ak.w += pe * kv.w;
        float ex = fmaxf(kv.x, 0.f) + __expf(fminf(kv.x, 0.f)) - 1.f;
        float ey = fmaxf(kv.y, 0.f) + __expf(fminf(kv.y, 0.f)) - 1.f;
        float ez = fmaxf(kv.z, 0.f) + __expf(fminf(kv.z, 0.f)) - 1.f;
        float ew = fmaxf(kv.w, 0.f) + __expf(fminf(kv.w, 0.f)) - 1.f;
        av.x += pe * ex; av.y += pe * ey; av.z += pe * ez; av.w += pe * ew;
      }
    }
    *(float4*)&sk[s * 16 + 4 * q] = ak;
    *(float4*)&sv[s * 16 + 4 * q] = av;
  }
  __syncthreads();
  if (t < 100) {
    const float* qp = &fb[(m * 100 + t) * 96];
    float4 q0 = *(const float4*)&qp[0];
    float4 q1 = *(const float4*)&qp[4];
    float4 q2 = *(const float4*)&qp[8];
    float4 q3 = *(const float4*)&qp[12];
    q0.x *= ITEMP; q0.y *= ITEMP; q0.z *= ITEMP; q0.w *= ITEMP;
    q1.x *= ITEMP; q1.y *= ITEMP; q1.z *= ITEMP; q1.w *= ITEMP;
    q2.x *= ITEMP; q2.y *= ITEMP; q2.z *= ITEMP; q2.w *= ITEMP;
    q3.x *= ITEMP; q3.y *= ITEMP; q3.z *= ITEMP; q3.w *= ITEMP;
    float4 z4 = make_float4(0.f, 0.f, 0.f, 0.f);
    float4 oa0 = z4, oa1 = z4, oa2 = z4, oa3 = z4;
    float4 ob0 = z4, ob1 = z4, ob2 = z4, ob3 = z4;
    float mmax = -3.4e38f, lsa = 0.f, lsb = 0.f;
    for (int tt = 0; tt < 100; tt += 2) {
      const float* ska = &sk[tt * 16];
      float4 ka0 = *(const float4*)&ska[0];
      float4 ka1 = *(const float4*)&ska[4];
      float4 ka2 = *(const float4*)&ska[8];
      float4 ka3 = *(const float4*)&ska[12];
      float4 kb0 = *(const float4*)&ska[16];
      float4 kb1 = *(const float4*)&ska[20];
      float4 kb2 = *(const float4*)&ska[24];
      float4 kb3 = *(const float4*)&ska[28];
      float sa = q0.x * ka0.x + q0.y * ka0.y + q0.z * ka0.z + q0.w * ka0.w
               + q1.x * ka1.x + q1.y * ka1.y + q1.z * ka1.z + q1.w * ka1.w
               + q2.x * ka2.x + q2.y * ka2.y + q2.z * ka2.z + q2.w * ka2.w
               + q3.x * ka3.x + q3.y * ka3.y + q3.z * ka3.z + q3.w * ka3.w;
      float sb = q0.x * kb0.x + q0.y * kb0.y + q0.z * kb0.z + q0.w * kb0.w
               + q1.x * kb1.x + q1.y * kb1.y + q1.z * kb1.z + q1.w * kb1.w
               + q2.x * kb2.x + q2.y * kb2.y + q2.z * kb2.z + q2.w * kb2.w
               + q3.x * kb3.x + q3.y * kb3.y + q3.z * kb3.z + q3.w * kb3.w;
      float pm = fmaxf(sa, sb);
      float dmx = pm - mmax;
      if (dmx > 8.f) {             // defer-rescale (T13), ~1-2 times total
        float scal = __expf(-dmx); // mmax may be -3.4e38: exp(-huge)=0, ok
        lsa *= scal; lsb *= scal;
        oa0.x *= scal; oa0.y *= scal; oa0.z *= scal; oa0.w *= scal;
        oa1.x *= scal; oa1.y *= scal; oa1.z *= scal; oa1.w *= scal;
        oa2.x *= scal; oa2.y *= scal; oa2.z *= scal; oa2.w *= scal;
        oa3.x *= scal; oa3.y *= scal; oa3.z *= scal; oa3.w *= scal;
        ob0.x *= scal; ob0.y *= scal; ob0.z *= scal; ob0.w *= scal;
        ob1.x *= scal; ob1.y *= scal; ob1.z *= scal; ob1.w *= scal;
        ob2.x *= scal; ob2.y *= scal; ob2.z *= scal; ob2.w *= scal;
        ob3.x *= scal; ob3.y *= scal; ob3.z *= scal; ob3.w *= scal;
        mmax = pm;
      }
      float ea = __expf(sa - mmax);
      float eb = __expf(sb - mmax);
      lsa += ea; lsb += eb;
      const float* sva = &sv[tt * 16];
      float4 va0 = *(const float4*)&sva[0];
      float4 va1 = *(const float4*)&sva[4];
      float4 va2 = *(const float4*)&sva[8];
      float4 va3 = *(const float4*)&sva[12];
      float4 vb0 = *(const float4*)&sva[16];
      float4 vb1 = *(const float4*)&sva[20];
      float4 vb2 = *(const float4*)&sva[24];
      float4 vb3 = *(const float4*)&sva[28];
      oa0.x += ea * va0.x; oa0.y += ea * va0.y; oa0.z += ea * va0.z; oa0.w += ea * va0.w;
      oa1.x += ea * va1.x; oa1.y += ea * va1.y; oa1.z += ea * va1.z; oa1.w += ea * va1.w;
      oa2.x += ea * va2.x; oa2.y += ea * va2.y; oa2.z += ea * va2.z; oa2.w += ea * va2.w;
      oa3.x += ea * va3.x; oa3.y += ea * va3.y; oa3.z += ea * va3.z; oa3.w += ea * va3.w;
      ob0.x += eb * vb0.x; ob0.y += eb * vb0.y; ob0.z += eb * vb0.z; ob0.w += eb * vb0.w;
      ob1.x += eb * vb1.x; ob1.y += eb * vb1.y; ob1.z += eb * vb1.z; ob1.w += eb * vb1.w;
      ob2.x += eb * vb2.x; ob2.y += eb * vb2.y; ob2.z += eb * vb2.z; ob2.w += eb * vb2.w;
      ob3.x += eb * vb3.x; ob3.y += eb * vb3.y; ob3.z += eb * vb3.z; ob3.w += eb * vb3.w;
    }
    float ri = 1.f / (lsa + lsb);
    float* ob = out + b * CNW + c * 96000 + gr * 16 + (m * 100 + t) * 96;
    float4 w0 = make_float4((oa0.x + ob0.x) * ri, (oa0.y + ob0.y) * ri,
                            (oa0.z + ob0.z) * ri, (oa0.w + ob0.w) * ri);
    float4 w1 = make_float4((oa1.x + ob1.x) * ri, (oa1.y + ob1.y) * ri,
                            (oa1.z + ob1.z) * ri, (oa1.w + ob1.w) * ri);
    float4 w2 = make_float4((oa2.x + ob2.x) * ri, (oa2.y + ob2.y) * ri,
                            (oa2.z + ob2.z) * ri, (oa2.w + ob2.w) * ri);
    float4 w3 = make_float4((oa3.x + ob3.x) * ri, (oa3.y + ob3.y) * ri,
                            (oa3.z + ob3.z) * ri, (oa3.w + ob3.w) * ri);
    *(float4*)&ob[0]  = w0;
    *(float4*)&ob[4]  = w1;
    *(float4*)&ob[8]  = w2;
    *(float4*)&ob[12] = w3;
  }
}

// ------- t = swapaxes(feat_attn,1,3) + x, fused GN group stats --------------
__global__ __launch_bounds__(256) void trans_add_k(const float* __restrict__ z,
    const float* __restrict__ x, float* __restrict__ out, float* __restrict__ st) {
  __shared__ float ld[96 * 97];
  __shared__ float red[12];
  int b = blockIdx.x / 1000, n = blockIdx.x % 1000;
  int t = threadIdx.x;
  if (t < 12) red[t] = 0.f;
  const float* zp = z + b * CNW + n * 96;
  for (int i = t; i < 9216; i += 256) {
    int r = i / 96, col = i % 96;
    ld[r * 97 + col] = zp[r * 96000 + col];
  }
  __syncthreads();
  const float* xp = x + b * CNW + n * 96;
  float* op = out + b * CNW + n * 96;
  float s = 0.f, q = 0.f;
  int gc = t / 1536;            // group of first element (g = i/1536)
  for (int i = t; i < 9216; i += 256) {
    int g = i / 1536;
    if (g != gc) {
      atomicAdd(&red[gc * 2 + 0], s);
      atomicAdd(&red[gc * 2 + 1], q);
      s = 0.f; q = 0.f; gc = g;
    }
    int cc = i / 96, ww = i % 96;
    float val = ld[ww * 97 + cc] + xp[cc * 96000 + ww];
    op[cc * 96000 + ww] = val;
    s += val; q += val * val;
  }
  atomicAdd(&red[gc * 2 + 0], s);
  atomicAdd(&red[gc * 2 + 1], q);
  __syncthreads();
  if (t < 12) atomicAdd(&st[b * 12 + t], red[t]);
}

// ---------------- out = relu( BN2(IN(l2)) + BNr(right_raw) ) -----------------
__global__ __launch_bounds__(256) void final_k(float* __restrict__ outp,
    const float* __restrict__ l2, const float* __restrict__ stR,
    const float* __restrict__ st2, const float* __restrict__ rw,
    const float* __restrict__ rb, const float* __restrict__ w2,
    const float* __restrict__ b2) {
  int stride = gridDim.x * 256;
  for (int i4 = blockIdx.x * 256 + threadIdx.x; i4 < 4608000; i4 += stride) {
    int i = i4 * 4;
    int b = i / CNW, o = (i / 96000) % 96;
    float mr = stR[o * 2] * (1.f / 192000.f);
    float vr = stR[o * 2 + 1] * (1.f / 192000.f) - mr * mr;
    float rs = rsqrtf(vr + EPSV) * rw[o];
    float rsh = rb[o] - mr * rs;
    const float inv = 1.f / 96000.f;
    float m0 = st2[o * 2] * inv,        v0 = st2[o * 2 + 1] * inv - m0 * m0;
    float m1 = st2[(96 + o) * 2] * inv, v1 = st2[(96 + o) * 2 + 1] * inv - m1 * m1;
    float bv = 0.5f * (v0 / (v0 + EPSV) + v1 / (v1 + EPSV));
    float ls = rsqrtf(bv + EPSV) * w2[o];
    float mi = b ? m1 : m0, vi = b ? v1 : v0;
    float lsc = rsqrtf(vi + EPSV) * ls;
    float lsh = b2[o] - mi * lsc;
    float4 R = ((float4*)outp)[i4];
    float4 L = ((const float4*)l2)[i4];
    float4 O;
    O.x = fmaxf(R.x * rs + rsh + L.x * lsc + lsh, 0.f);
    O.y = fmaxf(R.y * rs + rsh + L.y * lsc + lsh, 0.f);
    O.z = fmaxf(R.z * rs + rsh + L.z * lsc + lsh, 0.f);
    O.w = fmaxf(R.w * rs + rsh + L.w * lsc + lsh, 0.f);
    ((float4*)outp)[i4] = O;
  }
}

extern "C" void kernel_launch(void* const* d_in, const int* in_sizes, int n_in,
                              void* d_out, int out_size, void* d_ws, size_t ws_size,
                              hipStream_t stream) {
  const float* x        = (const float*)d_in[0];
  const float* w_linear = (const float*)d_in[1];
  const float* gn_w     = (const float*)d_in[2];
  const float* gn_b     = (const float*)d_in[3];
  const float* w_right  = (const float*)d_in[4];
  const float* b_right  = (const float*)d_in[5];
  const float* bn_r_w   = (const float*)d_in[6];
  const float* bn_r_b   = (const float*)d_in[7];
  const float* w_l1     = (const float*)d_in[8];
  const float* b_l1     = (const float*)d_in[9];
  const float* bn1_w    = (const float*)d_in[10];
  const float* bn1_b    = (const float*)d_in[11];
  const float* w_l2     = (const float*)d_in[12];
  const float* b_l2     = (const float*)d_in[13];
  const float* bn2_w    = (const float*)d_in[14];
  const float* bn2_b    = (const float*)d_in[15];
  float* out = (float*)d_out;

  float* A     = (float*)d_ws;          // 18,432,000 floats
  float* Bb    = A + TOT;               // 18,432,000 floats
  float* Pg    = Bb + TOT;              // 115,200 floats
  float* stGN  = Pg + 115200;           // 24
  float* stBNr = stGN + 24;             // 192
  float* stIN1 = stBNr + 192;           // 384
  float* stIN2 = stIN1 + 384;           // 384

  hipMemsetAsync(stGN, 0, 984 * sizeof(float), stream);

  // feat = conv1x1(x, w_linear)  -> A
  conv_k<0, 0><<<2000, 256, 0, stream>>>(x, w_linear, nullptr, A,
                                         nullptr, nullptr, nullptr, nullptr);
  // block means + sinkhorn + top-3 cut -> P
  attnA_k<<<1152, 256, 0, stream>>>(A, Pg);
  // attention -> Bb ([B,C,N,W] layout)
  attnB_k<<<11520, 128, 0, stream>>>(A, Pg, Bb);
  // t = swapaxes(feat_attn,1,3) + x -> A ; fused GN stats -> stGN
  trans_add_k<<<2000, 256, 0, stream>>>(Bb, x, A, stGN);
  // right = conv(GN(y), w_right)+b -> d_out (raw), GN folded; fused BN stats
  conv_k<1, 1><<<2000, 256, 0, stream>>>(A, w_right, b_right, out,
                                         stGN, gn_w, gn_b, stBNr);
  // l1 = conv(GN(y), w_l1)+b -> Bb (raw), GN folded; fused per-(b,o) IN stats
  conv_k<1, 2><<<2000, 256, 0, stream>>>(A, w_l1, b_l1, Bb,
                                         stGN, gn_w, gn_b, stIN1);
  // l2 = conv(relu(BN1(IN(l1))), w_l2)+b -> A (raw), input fold; IN stats
  conv_k<2, 2><<<2000, 256, 0, stream>>>(Bb, w_l2, b_l2, A,
                                         stIN1, bn1_w, bn1_b, stIN2);
  // out = relu(BN2(IN(l2)) + BNr(right_raw))
  final_k<<<2048, 256, 0, stream>>>(out, A, stBNr, stIN2,
                                    bn_r_w, bn_r_b, bn2_w, bn2_b);
}

// Round 7
// 832.054 us; speedup vs baseline: 1.0206x; 1.0206x over previous
//
#include <hip/hip_runtime.h>
#include <math.h>

#define CNW 9216000      // C*N*W = 96*1000*96
#define TOT 18432000     // B*C*N*W
#define EPSV 1e-5f
#define ITEMP 0.10206207261596575f   // 1/sqrt(96)

// ---------------- conv1x1 with optional fused pre/post transforms -----------
// MODE 0: plain conv (+bias)
// MODE 1: GN-fold — weights scaled by per-(b,c) GN scale; GN shift folded into
//         bias via u-trick: out = W'@a + (bias + W'@u), u = sh/scv. st_in=stGN.
// MODE 2: input transform x' = relu(x*scl[b,c]+shf[b,c]) (BN1(IN) fold). st_in=stIN1.
// STATS 0: none; 1: per-channel sums to st_out[o*2..]; 2: per-(b,o) sums.
// Stats use a contention-free two-stage reduce through the dead xt tile
// (12 LDS-atomicAdds/thread with 24-way same-address contention doubled conv
//  time in R6 — LDS atomic RMWs serialize).
template <int MODE, int STATS>
__global__ __launch_bounds__(256) void conv_k(const float* __restrict__ x,
    const float* __restrict__ w, const float* __restrict__ bias,
    float* __restrict__ out, const float* __restrict__ st_in,
    const float* __restrict__ aw, const float* __restrict__ ab,
    float* __restrict__ st_out) {
  __shared__ float xt[96 * 100];
  __shared__ float wt[96 * 100];
  __shared__ float scl[96], shf[96], bias2[96];
  int b = blockIdx.x / 1000, n = blockIdx.x % 1000;
  int t = threadIdx.x;
  if (MODE == 1) {
    if (t < 96) {
      int g = t >> 4;
      float m = st_in[(b * 6 + g) * 2] * (1.f / 1536000.f);
      float v = st_in[(b * 6 + g) * 2 + 1] * (1.f / 1536000.f) - m * m;
      float sc = rsqrtf(v + EPSV) * aw[t];
      float sh = ab[t] - m * sc;
      scl[t] = sc;
      shf[t] = sh / sc;          // u[c]
    }
    __syncthreads();
  } else if (MODE == 2) {
    if (t < 96) {
      const float inv = 1.f / 96000.f;
      float m0 = st_in[t * 2] * inv, v0 = st_in[t * 2 + 1] * inv - m0 * m0;
      float m1 = st_in[(96 + t) * 2] * inv, v1 = st_in[(96 + t) * 2 + 1] * inv - m1 * m1;
      float bv = 0.5f * (v0 / (v0 + EPSV) + v1 / (v1 + EPSV));
      float bscale = rsqrtf(bv + EPSV) * aw[t];
      float mi = b ? m1 : m0, vi = b ? v1 : v0;
      float sc = rsqrtf(vi + EPSV) * bscale;
      scl[t] = sc;
      shf[t] = ab[t] - mi * sc;
    }
    __syncthreads();
  }
  const float* xp = x + b * CNW + n * 96;
  for (int i = t; i < 9216; i += 256) {
    int cc = i / 96, j = i % 96;
    float xv = xp[cc * 96000 + j];
    if (MODE == 2) xv = fmaxf(xv * scl[cc] + shf[cc], 0.f);
    xt[cc * 100 + j] = xv;
    float wv = w[i];               // i = o*96 + c : o=cc, c=j
    if (MODE == 1) wv *= scl[j];
    wt[cc * 100 + j] = wv;
  }
  __syncthreads();
  // idle wave computes the folded bias for MODE 1 (concurrent with compute)
  if (MODE == 1 && t >= 192) {
    for (int o = t - 192; o < 96; o += 64) {
      float acc = bias ? bias[o] : 0.f;
      for (int c2 = 0; c2 < 96; ++c2) acc += wt[o * 100 + c2] * shf[c2];
      bias2[o] = acc;
    }
  }
  float4 acc[12];
#pragma unroll
  for (int oo = 0; oo < 12; ++oo) acc[oo] = make_float4(0.f, 0.f, 0.f, 0.f);
  int wq = t % 24, og = t / 24;       // w = 4*wq+r, o = og*12+oo
  if (t < 192) {
    for (int cq = 0; cq < 24; ++cq) {
      float4 xv0 = *(const float4*)&xt[(4 * cq + 0) * 100 + 4 * wq];
      float4 xv1 = *(const float4*)&xt[(4 * cq + 1) * 100 + 4 * wq];
      float4 xv2 = *(const float4*)&xt[(4 * cq + 2) * 100 + 4 * wq];
      float4 xv3 = *(const float4*)&xt[(4 * cq + 3) * 100 + 4 * wq];
#pragma unroll
      for (int oo = 0; oo < 12; ++oo) {
        int o = og * 12 + oo;
        float4 wv = *(const float4*)&wt[o * 100 + 4 * cq];
        acc[oo].x += wv.x * xv0.x + wv.y * xv1.x + wv.z * xv2.x + wv.w * xv3.x;
        acc[oo].y += wv.x * xv0.y + wv.y * xv1.y + wv.z * xv2.y + wv.w * xv3.y;
        acc[oo].z += wv.x * xv0.z + wv.y * xv1.z + wv.z * xv2.z + wv.w * xv3.z;
        acc[oo].w += wv.x * xv0.w + wv.y * xv1.w + wv.z * xv2.w + wv.w * xv3.w;
      }
    }
  }
  __syncthreads();     // bias2 ready; xt free for reuse (all reads done)
  if (t < 192) {
    float* op = out + b * CNW + n * 96 + 4 * wq;
    float sp[12], qp[12];
#pragma unroll
    for (int oo = 0; oo < 12; ++oo) {
      int o = og * 12 + oo;
      float4 v = acc[oo];
      float bb = (MODE == 1) ? bias2[o] : (bias ? bias[o] : 0.f);
      v.x += bb; v.y += bb; v.z += bb; v.w += bb;
      *(float4*)&op[o * 96000] = v;
      if (STATS) {
        sp[oo] = v.x + v.y + v.z + v.w;
        qp[oo] = v.x * v.x + v.y * v.y + v.z * v.z + v.w * v.w;
      }
    }
    if (STATS) {
#pragma unroll
      for (int oo = 0; oo < 12; ++oo) {
        int o = og * 12 + oo;
        xt[o * 100 + wq] = sp[oo];        // contention-free scatter
        xt[o * 100 + 50 + wq] = qp[oo];
      }
    }
  }
  if (STATS) {
    __syncthreads();
    if (t < 96) {
      float S = 0.f, Q = 0.f;
      for (int w2 = 0; w2 < 24; ++w2) {
        S += xt[t * 100 + w2];
        Q += xt[t * 100 + 50 + w2];
      }
      int base = (STATS == 2) ? b * 192 : 0;
      atomicAdd(&st_out[base + t * 2 + 0], S);
      atomicAdd(&st_out[base + t * 2 + 1], Q);
    }
  }
}

// ---------------- attention kernel A: block means -> sinkhorn -> top3 cut -> P
__global__ __launch_bounds__(256) void attnA_k(const float* __restrict__ feat,
                                               float* __restrict__ Pg) {
  int head = blockIdx.x;
  int b = head / 576, rem = head % 576, c = rem / 6, gr = rem % 6;
  const float* fb = feat + b * CNW + c * 96000 + gr * 16;
  __shared__ float qm[160];     // [10][16]
  __shared__ float L[110];      // [10][11]
  int t = threadIdx.x;
  if (t < 160) {
    int m = t / 16, j = t % 16;
    float s = 0.f;
    for (int ss = 0; ss < 100; ++ss) s += fb[(m * 100 + ss) * 96 + j];
    qm[m * 16 + j] = s * 0.01f;
  }
  __syncthreads();
  if (t < 100) {
    int m = t / 10, n2 = t % 10;
    float acc = 0.f;
#pragma unroll
    for (int j = 0; j < 16; ++j) acc += qm[m * 16 + j] * qm[n2 * 16 + j];
    L[m * 11 + n2] = acc * ITEMP;
  }
  __syncthreads();
  for (int it = 0; it < 8; ++it) {
    if (t < 10) {   // row LSE (axis=-1)
      float mx = -3.4e38f;
      for (int n2 = 0; n2 < 10; ++n2) mx = fmaxf(mx, L[t * 11 + n2]);
      float s = 0.f;
      for (int n2 = 0; n2 < 10; ++n2) s += expf(L[t * 11 + n2] - mx);
      float lse = mx + logf(s);
      for (int n2 = 0; n2 < 10; ++n2) L[t * 11 + n2] -= lse;
    }
    __syncthreads();
    if (t < 10) {   // col LSE (axis=-2)
      float mx = -3.4e38f;
      for (int m = 0; m < 10; ++m) mx = fmaxf(mx, L[m * 11 + t]);
      float s = 0.f;
      for (int m = 0; m < 10; ++m) s += expf(L[m * 11 + t] - mx);
      float lse = mx + logf(s);
      for (int m = 0; m < 10; ++m) L[m * 11 + t] -= lse;
    }
    __syncthreads();
  }
  if (t < 10) {
    float p[10];
#pragma unroll
    for (int n2 = 0; n2 < 10; ++n2) p[n2] = expf(L[t * 11 + n2]);
    int i1 = -1, i2 = -1;
    float m1 = -1.f, m2 = -1.f, m3 = -1.f;
#pragma unroll
    for (int n2 = 0; n2 < 10; ++n2) if (p[n2] > m1) { m1 = p[n2]; i1 = n2; }
#pragma unroll
    for (int n2 = 0; n2 < 10; ++n2) if (n2 != i1 && p[n2] > m2) { m2 = p[n2]; i2 = n2; }
#pragma unroll
    for (int n2 = 0; n2 < 10; ++n2) if (n2 != i1 && n2 != i2 && p[n2] > m3) m3 = p[n2];
#pragma unroll
    for (int n2 = 0; n2 < 10; ++n2)
      Pg[head * 100 + t * 10 + n2] = (p[n2] >= m3) ? p[n2] : 0.f;
  }
}

// ---------------- attention kernel B (flash-style, ILP-2 over keys) ---------
// head-major decode: the 10 m-blocks of a head are dispatch-adjacent -> their
// shared K/V rows stay L2-hot (m-major decode in R6 raised FETCH 187->233 MB).
__global__ __launch_bounds__(128) void attnB_k(const float* __restrict__ feat,
    const float* __restrict__ Pg, float* __restrict__ out) {
  int m = blockIdx.x % 10;
  int head = blockIdx.x / 10;
  int b = head / 576, rem = head % 576, c = rem / 6, gr = rem % 6;
  const float* fb = feat + b * CNW + c * 96000 + gr * 16;
  __shared__ float sk[100 * 16];
  __shared__ float sv[100 * 16];
  int t = threadIdx.x;
  float p[10];
#pragma unroll
  for (int n2 = 0; n2 < 10; ++n2) p[n2] = Pg[head * 100 + m * 10 + n2];
  // build mixed sk/sv (v = elu(k), branchless)
  for (int i4 = t; i4 < 400; i4 += 128) {
    int s = i4 >> 2, q = i4 & 3;
    float4 ak = make_float4(0.f, 0.f, 0.f, 0.f);
    float4 av = make_float4(0.f, 0.f, 0.f, 0.f);
#pragma unroll
    for (int n2 = 0; n2 < 10; ++n2) {
      if (p[n2] != 0.f) {
        float4 kv = *(const float4*)&fb[(n2 * 100 + s) * 96 + 4 * q];
        float pe = p[n2];
        ak.x += pe * kv.x; ak.y += pe * kv.y; ak.z += pe * kv.z; ak.w += pe * kv.w;
        float ex = fmaxf(kv.x, 0.f) + __expf(fminf(kv.x, 0.f)) - 1.f;
        float ey = fmaxf(kv.y, 0.f) + __expf(fminf(kv.y, 0.f)) - 1.f;
        float ez = fmaxf(kv.z, 0.f) + __expf(fminf(kv.z, 0.f)) - 1.f;
        float ew = fmaxf(kv.w, 0.f) + __expf(fminf(kv.w, 0.f)) - 1.f;
        av.x += pe * ex; av.y += pe * ey; av.z += pe * ez; av.w += pe * ew;
      }
    }
    *(float4*)&sk[s * 16 + 4 * q] = ak;
    *(float4*)&sv[s * 16 + 4 * q] = av;
  }
  __syncthreads();
  if (t < 100) {
    const float* qp = &fb[(m * 100 + t) * 96];
    float4 q0 = *(const float4*)&qp[0];
    float4 q1 = *(const float4*)&qp[4];
    float4 q2 = *(const float4*)&qp[8];
    float4 q3 = *(const float4*)&qp[12];
    q0.x *= ITEMP; q0.y *= ITEMP; q0.z *= ITEMP; q0.w *= ITEMP;
    q1.x *= ITEMP; q1.y *= ITEMP; q1.z *= ITEMP; q1.w *= ITEMP;
    q2.x *= ITEMP; q2.y *= ITEMP; q2.z *= ITEMP; q2.w *= ITEMP;
    q3.x *= ITEMP; q3.y *= ITEMP; q3.z *= ITEMP; q3.w *= ITEMP;
    float4 z4 = make_float4(0.f, 0.f, 0.f, 0.f);
    float4 oa0 = z4, oa1 = z4, oa2 = z4, oa3 = z4;
    float4 ob0 = z4, ob1 = z4, ob2 = z4, ob3 = z4;
    float mmax = -3.4e38f, lsa = 0.f, lsb = 0.f;
    for (int tt = 0; tt < 100; tt += 2) {
      const float* ska = &sk[tt * 16];
      float4 ka0 = *(const float4*)&ska[0];
      float4 ka1 = *(const float4*)&ska[4];
      float4 ka2 = *(const float4*)&ska[8];
      float4 ka3 = *(const float4*)&ska[12];
      float4 kb0 = *(const float4*)&ska[16];
      float4 kb1 = *(const float4*)&ska[20];
      float4 kb2 = *(const float4*)&ska[24];
      float4 kb3 = *(const float4*)&ska[28];
      float sa = q0.x * ka0.x + q0.y * ka0.y + q0.z * ka0.z + q0.w * ka0.w
               + q1.x * ka1.x + q1.y * ka1.y + q1.z * ka1.z + q1.w * ka1.w
               + q2.x * ka2.x + q2.y * ka2.y + q2.z * ka2.z + q2.w * ka2.w
               + q3.x * ka3.x + q3.y * ka3.y + q3.z * ka3.z + q3.w * ka3.w;
      float sb = q0.x * kb0.x + q0.y * kb0.y + q0.z * kb0.z + q0.w * kb0.w
               + q1.x * kb1.x + q1.y * kb1.y + q1.z * kb1.z + q1.w * kb1.w
               + q2.x * kb2.x + q2.y * kb2.y + q2.z * kb2.z + q2.w * kb2.w
               + q3.x * kb3.x + q3.y * kb3.y + q3.z * kb3.z + q3.w * kb3.w;
      float pm = fmaxf(sa, sb);
      float dmx = pm - mmax;
      if (dmx > 8.f) {             // defer-rescale (T13), ~1-2 times total
        float scal = __expf(-dmx); // mmax may be -3.4e38: exp(-huge)=0, ok
        lsa *= scal; lsb *= scal;
        oa0.x *= scal; oa0.y *= scal; oa0.z *= scal; oa0.w *= scal;
        oa1.x *= scal; oa1.y *= scal; oa1.z *= scal; oa1.w *= scal;
        oa2.x *= scal; oa2.y *= scal; oa2.z *= scal; oa2.w *= scal;
        oa3.x *= scal; oa3.y *= scal; oa3.z *= scal; oa3.w *= scal;
        ob0.x *= scal; ob0.y *= scal; ob0.z *= scal; ob0.w *= scal;
        ob1.x *= scal; ob1.y *= scal; ob1.z *= scal; ob1.w *= scal;
        ob2.x *= scal; ob2.y *= scal; ob2.z *= scal; ob2.w *= scal;
        ob3.x *= scal; ob3.y *= scal; ob3.z *= scal; ob3.w *= scal;
        mmax = pm;
      }
      float ea = __expf(sa - mmax);
      float eb = __expf(sb - mmax);
      lsa += ea; lsb += eb;
      const float* sva = &sv[tt * 16];
      float4 va0 = *(const float4*)&sva[0];
      float4 va1 = *(const float4*)&sva[4];
      float4 va2 = *(const float4*)&sva[8];
      float4 va3 = *(const float4*)&sva[12];
      float4 vb0 = *(const float4*)&sva[16];
      float4 vb1 = *(const float4*)&sva[20];
      float4 vb2 = *(const float4*)&sva[24];
      float4 vb3 = *(const float4*)&sva[28];
      oa0.x += ea * va0.x; oa0.y += ea * va0.y; oa0.z += ea * va0.z; oa0.w += ea * va0.w;
      oa1.x += ea * va1.x; oa1.y += ea * va1.y; oa1.z += ea * va1.z; oa1.w += ea * va1.w;
      oa2.x += ea * va2.x; oa2.y += ea * va2.y; oa2.z += ea * va2.z; oa2.w += ea * va2.w;
      oa3.x += ea * va3.x; oa3.y += ea * va3.y; oa3.z += ea * va3.z; oa3.w += ea * va3.w;
      ob0.x += eb * vb0.x; ob0.y += eb * vb0.y; ob0.z += eb * vb0.z; ob0.w += eb * vb0.w;
      ob1.x += eb * vb1.x; ob1.y += eb * vb1.y; ob1.z += eb * vb1.z; ob1.w += eb * vb1.w;
      ob2.x += eb * vb2.x; ob2.y += eb * vb2.y; ob2.z += eb * vb2.z; ob2.w += eb * vb2.w;
      ob3.x += eb * vb3.x; ob3.y += eb * vb3.y; ob3.z += eb * vb3.z; ob3.w += eb * vb3.w;
    }
    float ri = 1.f / (lsa + lsb);
    float* ob = out + b * CNW + c * 96000 + gr * 16 + (m * 100 + t) * 96;
    float4 w0 = make_float4((oa0.x + ob0.x) * ri, (oa0.y + ob0.y) * ri,
                            (oa0.z + ob0.z) * ri, (oa0.w + ob0.w) * ri);
    float4 w1 = make_float4((oa1.x + ob1.x) * ri, (oa1.y + ob1.y) * ri,
                            (oa1.z + ob1.z) * ri, (oa1.w + ob1.w) * ri);
    float4 w2 = make_float4((oa2.x + ob2.x) * ri, (oa2.y + ob2.y) * ri,
                            (oa2.z + ob2.z) * ri, (oa2.w + ob2.w) * ri);
    float4 w3 = make_float4((oa3.x + ob3.x) * ri, (oa3.y + ob3.y) * ri,
                            (oa3.z + ob3.z) * ri, (oa3.w + ob3.w) * ri);
    *(float4*)&ob[0]  = w0;
    *(float4*)&ob[4]  = w1;
    *(float4*)&ob[8]  = w2;
    *(float4*)&ob[12] = w3;
  }
}

// ---------------- t = swapaxes(feat_attn,1,3) + x  (per (b,n) 96x96 tile) ----
__global__ __launch_bounds__(256) void trans_add_k(const float* __restrict__ z,
    const float* __restrict__ x, float* __restrict__ out) {
  __shared__ float ld[96 * 97];
  int b = blockIdx.x / 1000, n = blockIdx.x % 1000;
  int t = threadIdx.x;
  const float* zp = z + b * CNW + n * 96;
  for (int i = t; i < 9216; i += 256) {
    int r = i / 96, col = i % 96;
    ld[r * 97 + col] = zp[r * 96000 + col];
  }
  __syncthreads();
  const float* xp = x + b * CNW + n * 96;
  float* op = out + b * CNW + n * 96;
  for (int i = t; i < 9216; i += 256) {
    int cc = i / 96, ww = i % 96;
    op[cc * 96000 + ww] = ld[ww * 97 + cc] + xp[cc * 96000 + ww];
  }
}

// ---------------- GN stats: 12 contiguous (b,group) slices of 1.536M floats --
__global__ __launch_bounds__(256) void gnstats_k(const float* __restrict__ a,
                                                 float* __restrict__ st) {
  int slice = blockIdx.x >> 5, chunk = blockIdx.x & 31;
  const float4* p = (const float4*)(a + slice * 1536000 + chunk * 48000);
  float s = 0.f, q = 0.f;
  for (int i = threadIdx.x; i < 12000; i += 256) {
    float4 v = p[i];
    s += v.x + v.y + v.z + v.w;
    q += v.x * v.x + v.y * v.y + v.z * v.z + v.w * v.w;
  }
#pragma unroll
  for (int d = 32; d >= 1; d >>= 1) { s += __shfl_down(s, d, 64); q += __shfl_down(q, d, 64); }
  __shared__ float ls[4], lq[4];
  int wid = threadIdx.x >> 6;
  if ((threadIdx.x & 63) == 0) { ls[wid] = s; lq[wid] = q; }
  __syncthreads();
  if (threadIdx.x == 0) {
    atomicAdd(&st[slice * 2 + 0], ls[0] + ls[1] + ls[2] + ls[3]);
    atomicAdd(&st[slice * 2 + 1], lq[0] + lq[1] + lq[2] + lq[3]);
  }
}

// ---------------- out = relu( BN2(IN(l2)) + BNr(right_raw) ) -----------------
__global__ __launch_bounds__(256) void final_k(float* __restrict__ outp,
    const float* __restrict__ l2, const float* __restrict__ stR,
    const float* __restrict__ st2, const float* __restrict__ rw,
    const float* __restrict__ rb, const float* __restrict__ w2,
    const float* __restrict__ b2) {
  int stride = gridDim.x * 256;
  for (int i4 = blockIdx.x * 256 + threadIdx.x; i4 < 4608000; i4 += stride) {
    int i = i4 * 4;
    int b = i / CNW, o = (i / 96000) % 96;
    float mr = stR[o * 2] * (1.f / 192000.f);
    float vr = stR[o * 2 + 1] * (1.f / 192000.f) - mr * mr;
    float rs = rsqrtf(vr + EPSV) * rw[o];
    float rsh = rb[o] - mr * rs;
    const float inv = 1.f / 96000.f;
    float m0 = st2[o * 2] * inv,        v0 = st2[o * 2 + 1] * inv - m0 * m0;
    float m1 = st2[(96 + o) * 2] * inv, v1 = st2[(96 + o) * 2 + 1] * inv - m1 * m1;
    float bv = 0.5f * (v0 / (v0 + EPSV) + v1 / (v1 + EPSV));
    float ls = rsqrtf(bv + EPSV) * w2[o];
    float mi = b ? m1 : m0, vi = b ? v1 : v0;
    float lsc = rsqrtf(vi + EPSV) * ls;
    float lsh = b2[o] - mi * lsc;
    float4 R = ((float4*)outp)[i4];
    float4 L = ((const float4*)l2)[i4];
    float4 O;
    O.x = fmaxf(R.x * rs + rsh + L.x * lsc + lsh, 0.f);
    O.y = fmaxf(R.y * rs + rsh + L.y * lsc + lsh, 0.f);
    O.z = fmaxf(R.z * rs + rsh + L.z * lsc + lsh, 0.f);
    O.w = fmaxf(R.w * rs + rsh + L.w * lsc + lsh, 0.f);
    ((float4*)outp)[i4] = O;
  }
}

extern "C" void kernel_launch(void* const* d_in, const int* in_sizes, int n_in,
                              void* d_out, int out_size, void* d_ws, size_t ws_size,
                              hipStream_t stream) {
  const float* x        = (const float*)d_in[0];
  const float* w_linear = (const float*)d_in[1];
  const float* gn_w     = (const float*)d_in[2];
  const float* gn_b     = (const float*)d_in[3];
  const float* w_right  = (const float*)d_in[4];
  const float* b_right  = (const float*)d_in[5];
  const float* bn_r_w   = (const float*)d_in[6];
  const float* bn_r_b   = (const float*)d_in[7];
  const float* w_l1     = (const float*)d_in[8];
  const float* b_l1     = (const float*)d_in[9];
  const float* bn1_w    = (const float*)d_in[10];
  const float* bn1_b    = (const float*)d_in[11];
  const float* w_l2     = (const float*)d_in[12];
  const float* b_l2     = (const float*)d_in[13];
  const float* bn2_w    = (const float*)d_in[14];
  const float* bn2_b    = (const float*)d_in[15];
  float* out = (float*)d_out;

  float* A     = (float*)d_ws;          // 18,432,000 floats
  float* Bb    = A + TOT;               // 18,432,000 floats
  float* Pg    = Bb + TOT;              // 115,200 floats
  float* stGN  = Pg + 115200;           // 24
  float* stBNr = stGN + 24;             // 192
  float* stIN1 = stBNr + 192;           // 384
  float* stIN2 = stIN1 + 384;           // 384

  hipMemsetAsync(stGN, 0, 984 * sizeof(float), stream);

  // feat = conv1x1(x, w_linear)  -> A
  conv_k<0, 0><<<2000, 256, 0, stream>>>(x, w_linear, nullptr, A,
                                         nullptr, nullptr, nullptr, nullptr);
  // block means + sinkhorn + top-3 cut -> P
  attnA_k<<<1152, 256, 0, stream>>>(A, Pg);
  // attention -> Bb ([B,C,N,W] layout)
  attnB_k<<<11520, 128, 0, stream>>>(A, Pg, Bb);
  // t = swapaxes(feat_attn,1,3) + x -> A
  trans_add_k<<<2000, 256, 0, stream>>>(Bb, x, A);
  // GN group stats
  gnstats_k<<<384, 256, 0, stream>>>(A, stGN);
  // right = conv(GN(y), w_right)+b -> d_out (raw), GN folded; fused BN stats
  conv_k<1, 1><<<2000, 256, 0, stream>>>(A, w_right, b_right, out,
                                         stGN, gn_w, gn_b, stBNr);
  // l1 = conv(GN(y), w_l1)+b -> Bb (raw), GN folded; fused per-(b,o) IN stats
  conv_k<1, 2><<<2000, 256, 0, stream>>>(A, w_l1, b_l1, Bb,
                                         stGN, gn_w, gn_b, stIN1);
  // l2 = conv(relu(BN1(IN(l1))), w_l2)+b -> A (raw), input fold; IN stats
  conv_k<2, 2><<<2000, 256, 0, stream>>>(Bb, w_l2, b_l2, A,
                                         stIN1, bn1_w, bn1_b, stIN2);
  // out = relu(BN2(IN(l2)) + BNr(right_raw))
  final_k<<<2048, 256, 0, stream>>>(out, A, stBNr, stIN2,
                                    bn_r_w, bn_r_b, bn2_w, bn2_b);
}

// Round 8
// 625.069 us; speedup vs baseline: 1.3585x; 1.3311x over previous
//
#include <hip/hip_runtime.h>
#include <math.h>

#define CNW 9216000      // C*N*W = 96*1000*96
#define TOT 18432000     // B*C*N*W
#define EPSV 1e-5f
#define ITEMP 0.10206207261596575f   // 1/sqrt(96)
#define NREP 16          // stats replicas (breaks same-address atomic chains)

// ---------------- conv1x1 with optional fused pre/post transforms -----------
// MODE 0: plain conv (+bias)
// MODE 1: GN-fold — weights scaled by per-(b,c) GN scale; GN shift folded into
//         bias via u-trick: out = W'@a + (bias + W'@u), u = sh/scv. st_in=stGN.
// MODE 2: input transform x' = relu(x*scl[b,c]+shf[b,c]) (BN1(IN) fold),
//         st_in = canonical [b*192 + o*2 + j] stats.
// STATS 1: per-(b,o) sums into replicated raw buffer st_out[(n&15)*384 + b*192
//         + o*2 + j]. R6/R7 lesson: 2000 same-address global atomicAdd chains
//         serialize at L2 (~50us/conv); 16 replicas cut the chain to ~125.
template <int MODE, int STATS>
__global__ __launch_bounds__(256) void conv_k(const float* __restrict__ x,
    const float* __restrict__ w, const float* __restrict__ bias,
    float* __restrict__ out, const float* __restrict__ st_in,
    const float* __restrict__ aw, const float* __restrict__ ab,
    float* __restrict__ st_out) {
  __shared__ float xt[96 * 100];
  __shared__ float wt[96 * 100];
  __shared__ float scl[96], shf[96], bias2[96];
  int b = blockIdx.x / 1000, n = blockIdx.x % 1000;
  int t = threadIdx.x;
  if (MODE == 1) {
    if (t < 96) {
      int g = t >> 4;
      float m = st_in[(b * 6 + g) * 2] * (1.f / 1536000.f);
      float v = st_in[(b * 6 + g) * 2 + 1] * (1.f / 1536000.f) - m * m;
      float sc = rsqrtf(v + EPSV) * aw[t];
      float sh = ab[t] - m * sc;
      scl[t] = sc;
      shf[t] = sh / sc;          // u[c]
    }
    __syncthreads();
  } else if (MODE == 2) {
    if (t < 96) {
      const float inv = 1.f / 96000.f;
      float m0 = st_in[t * 2] * inv, v0 = st_in[t * 2 + 1] * inv - m0 * m0;
      float m1 = st_in[192 + t * 2] * inv, v1 = st_in[192 + t * 2 + 1] * inv - m1 * m1;
      float bv = 0.5f * (v0 / (v0 + EPSV) + v1 / (v1 + EPSV));
      float bscale = rsqrtf(bv + EPSV) * aw[t];
      float mi = b ? m1 : m0, vi = b ? v1 : v0;
      float sc = rsqrtf(vi + EPSV) * bscale;
      scl[t] = sc;
      shf[t] = ab[t] - mi * sc;
    }
    __syncthreads();
  }
  const float* xp = x + b * CNW + n * 96;
  for (int i = t; i < 9216; i += 256) {
    int cc = i / 96, j = i % 96;
    float xv = xp[cc * 96000 + j];
    if (MODE == 2) xv = fmaxf(xv * scl[cc] + shf[cc], 0.f);
    xt[cc * 100 + j] = xv;
    float wv = w[i];               // i = o*96 + c : o=cc, c=j
    if (MODE == 1) wv *= scl[j];
    wt[cc * 100 + j] = wv;
  }
  __syncthreads();
  // idle wave computes the folded bias for MODE 1 (concurrent with compute)
  if (MODE == 1 && t >= 192) {
    for (int o = t - 192; o < 96; o += 64) {
      float acc = bias ? bias[o] : 0.f;
      for (int c2 = 0; c2 < 96; ++c2) acc += wt[o * 100 + c2] * shf[c2];
      bias2[o] = acc;
    }
  }
  float4 acc[12];
#pragma unroll
  for (int oo = 0; oo < 12; ++oo) acc[oo] = make_float4(0.f, 0.f, 0.f, 0.f);
  int wq = t % 24, og = t / 24;       // w = 4*wq+r, o = og*12+oo
  if (t < 192) {
    for (int cq = 0; cq < 24; ++cq) {
      float4 xv0 = *(const float4*)&xt[(4 * cq + 0) * 100 + 4 * wq];
      float4 xv1 = *(const float4*)&xt[(4 * cq + 1) * 100 + 4 * wq];
      float4 xv2 = *(const float4*)&xt[(4 * cq + 2) * 100 + 4 * wq];
      float4 xv3 = *(const float4*)&xt[(4 * cq + 3) * 100 + 4 * wq];
#pragma unroll
      for (int oo = 0; oo < 12; ++oo) {
        int o = og * 12 + oo;
        float4 wv = *(const float4*)&wt[o * 100 + 4 * cq];
        acc[oo].x += wv.x * xv0.x + wv.y * xv1.x + wv.z * xv2.x + wv.w * xv3.x;
        acc[oo].y += wv.x * xv0.y + wv.y * xv1.y + wv.z * xv2.y + wv.w * xv3.y;
        acc[oo].z += wv.x * xv0.z + wv.y * xv1.z + wv.z * xv2.z + wv.w * xv3.z;
        acc[oo].w += wv.x * xv0.w + wv.y * xv1.w + wv.z * xv2.w + wv.w * xv3.w;
      }
    }
  }
  __syncthreads();     // bias2 ready; xt free for reuse (all reads done)
  if (t < 192) {
    float* op = out + b * CNW + n * 96 + 4 * wq;
    float sp[12], qp[12];
#pragma unroll
    for (int oo = 0; oo < 12; ++oo) {
      int o = og * 12 + oo;
      float4 v = acc[oo];
      float bb = (MODE == 1) ? bias2[o] : (bias ? bias[o] : 0.f);
      v.x += bb; v.y += bb; v.z += bb; v.w += bb;
      *(float4*)&op[o * 96000] = v;
      if (STATS) {
        sp[oo] = v.x + v.y + v.z + v.w;
        qp[oo] = v.x * v.x + v.y * v.y + v.z * v.z + v.w * v.w;
      }
    }
    if (STATS) {
#pragma unroll
      for (int oo = 0; oo < 12; ++oo) {
        int o = og * 12 + oo;
        xt[o * 100 + wq] = sp[oo];        // contention-free scatter
        xt[o * 100 + 50 + wq] = qp[oo];
      }
    }
  }
  if (STATS) {
    __syncthreads();
    if (t < 96) {
      float S = 0.f, Q = 0.f;
      for (int w2 = 0; w2 < 24; ++w2) {
        S += xt[t * 100 + w2];
        Q += xt[t * 100 + 50 + w2];
      }
      float* dst = st_out + (n & (NREP - 1)) * 384 + b * 192 + t * 2;
      atomicAdd(&dst[0], S);
      atomicAdd(&dst[1], Q);
    }
  }
}

// ---------------- collapse NREP replicas -> canonical [384] -----------------
// handles up to two buffers per launch (t<384 -> buf0, 384<=t<768 -> buf1)
__global__ __launch_bounds__(256) void collapse_k(const float* __restrict__ r0,
    float* __restrict__ o0, const float* __restrict__ r1, float* __restrict__ o1) {
  int t = blockIdx.x * 256 + threadIdx.x;
  const float* r = (t < 384) ? r0 : r1;
  float* o = (t < 384) ? o0 : o1;
  int i = (t < 384) ? t : t - 384;
  if (t < 768 && r) {
    float s = 0.f;
#pragma unroll
    for (int k = 0; k < NREP; ++k) s += r[k * 384 + i];
    o[i] = s;
  }
}

// ---------------- attention kernel A: block means -> sinkhorn -> top3 cut -> P
__global__ __launch_bounds__(256) void attnA_k(const float* __restrict__ feat,
                                               float* __restrict__ Pg) {
  int head = blockIdx.x;
  int b = head / 576, rem = head % 576, c = rem / 6, gr = rem % 6;
  const float* fb = feat + b * CNW + c * 96000 + gr * 16;
  __shared__ float qm[160];     // [10][16]
  __shared__ float L[110];      // [10][11]
  int t = threadIdx.x;
  if (t < 160) {
    int m = t / 16, j = t % 16;
    float s = 0.f;
    for (int ss = 0; ss < 100; ++ss) s += fb[(m * 100 + ss) * 96 + j];
    qm[m * 16 + j] = s * 0.01f;
  }
  __syncthreads();
  if (t < 100) {
    int m = t / 10, n2 = t % 10;
    float acc = 0.f;
#pragma unroll
    for (int j = 0; j < 16; ++j) acc += qm[m * 16 + j] * qm[n2 * 16 + j];
    L[m * 11 + n2] = acc * ITEMP;
  }
  __syncthreads();
  for (int it = 0; it < 8; ++it) {
    if (t < 10) {   // row LSE (axis=-1)
      float mx = -3.4e38f;
      for (int n2 = 0; n2 < 10; ++n2) mx = fmaxf(mx, L[t * 11 + n2]);
      float s = 0.f;
      for (int n2 = 0; n2 < 10; ++n2) s += expf(L[t * 11 + n2] - mx);
      float lse = mx + logf(s);
      for (int n2 = 0; n2 < 10; ++n2) L[t * 11 + n2] -= lse;
    }
    __syncthreads();
    if (t < 10) {   // col LSE (axis=-2)
      float mx = -3.4e38f;
      for (int m = 0; m < 10; ++m) mx = fmaxf(mx, L[m * 11 + t]);
      float s = 0.f;
      for (int m = 0; m < 10; ++m) s += expf(L[m * 11 + t] - mx);
      float lse = mx + logf(s);
      for (int m = 0; m < 10; ++m) L[m * 11 + t] -= lse;
    }
    __syncthreads();
  }
  if (t < 10) {
    float p[10];
#pragma unroll
    for (int n2 = 0; n2 < 10; ++n2) p[n2] = expf(L[t * 11 + n2]);
    int i1 = -1, i2 = -1;
    float m1 = -1.f, m2 = -1.f, m3 = -1.f;
#pragma unroll
    for (int n2 = 0; n2 < 10; ++n2) if (p[n2] > m1) { m1 = p[n2]; i1 = n2; }
#pragma unroll
    for (int n2 = 0; n2 < 10; ++n2) if (n2 != i1 && p[n2] > m2) { m2 = p[n2]; i2 = n2; }
#pragma unroll
    for (int n2 = 0; n2 < 10; ++n2) if (n2 != i1 && n2 != i2 && p[n2] > m3) m3 = p[n2];
#pragma unroll
    for (int n2 = 0; n2 < 10; ++n2)
      Pg[head * 100 + t * 10 + n2] = (p[n2] >= m3) ? p[n2] : 0.f;
  }
}

// ---------------- attention kernel B (flash-style, ILP-2 over keys) ---------
// head-major decode: the 10 m-blocks of a head are dispatch-adjacent -> their
// shared K/V rows stay L2-hot (m-major decode in R6 raised FETCH 187->233 MB).
__global__ __launch_bounds__(128) void attnB_k(const float* __restrict__ feat,
    const float* __restrict__ Pg, float* __restrict__ out) {
  int m = blockIdx.x % 10;
  int head = blockIdx.x / 10;
  int b = head / 576, rem = head % 576, c = rem / 6, gr = rem % 6;
  const float* fb = feat + b * CNW + c * 96000 + gr * 16;
  __shared__ float sk[100 * 16];
  __shared__ float sv[100 * 16];
  int t = threadIdx.x;
  float p[10];
#pragma unroll
  for (int n2 = 0; n2 < 10; ++n2) p[n2] = Pg[head * 100 + m * 10 + n2];
  // build mixed sk/sv (v = elu(k), branchless)
  for (int i4 = t; i4 < 400; i4 += 128) {
    int s = i4 >> 2, q = i4 & 3;
    float4 ak = make_float4(0.f, 0.f, 0.f, 0.f);
    float4 av = make_float4(0.f, 0.f, 0.f, 0.f);
#pragma unroll
    for (int n2 = 0; n2 < 10; ++n2) {
      if (p[n2] != 0.f) {
        float4 kv = *(const float4*)&fb[(n2 * 100 + s) * 96 + 4 * q];
        float pe = p[n2];
        ak.x += pe * kv.x; ak.y += pe * kv.y; ak.z += pe * kv.z; ak.w += pe * kv.w;
        float ex = fmaxf(kv.x, 0.f) + __expf(fminf(kv.x, 0.f)) - 1.f;
        float ey = fmaxf(kv.y, 0.f) + __expf(fminf(kv.y, 0.f)) - 1.f;
        float ez = fmaxf(kv.z, 0.f) + __expf(fminf(kv.z, 0.f)) - 1.f;
        float ew = fmaxf(kv.w, 0.f) + __expf(fminf(kv.w, 0.f)) - 1.f;
        av.x += pe * ex; av.y += pe * ey; av.z += pe * ez; av.w += pe * ew;
      }
    }
    *(float4*)&sk[s * 16 + 4 * q] = ak;
    *(float4*)&sv[s * 16 + 4 * q] = av;
  }
  __syncthreads();
  if (t < 100) {
    const float* qp = &fb[(m * 100 + t) * 96];
    float4 q0 = *(const float4*)&qp[0];
    float4 q1 = *(const float4*)&qp[4];
    float4 q2 = *(const float4*)&qp[8];
    float4 q3 = *(const float4*)&qp[12];
    q0.x *= ITEMP; q0.y *= ITEMP; q0.z *= ITEMP; q0.w *= ITEMP;
    q1.x *= ITEMP; q1.y *= ITEMP; q1.z *= ITEMP; q1.w *= ITEMP;
    q2.x *= ITEMP; q2.y *= ITEMP; q2.z *= ITEMP; q2.w *= ITEMP;
    q3.x *= ITEMP; q3.y *= ITEMP; q3.z *= ITEMP; q3.w *= ITEMP;
    float4 z4 = make_float4(0.f, 0.f, 0.f, 0.f);
    float4 oa0 = z4, oa1 = z4, oa2 = z4, oa3 = z4;
    float4 ob0 = z4, ob1 = z4, ob2 = z4, ob3 = z4;
    float mmax = -3.4e38f, lsa = 0.f, lsb = 0.f;
    for (int tt = 0; tt < 100; tt += 2) {
      const float* ska = &sk[tt * 16];
      float4 ka0 = *(const float4*)&ska[0];
      float4 ka1 = *(const float4*)&ska[4];
      float4 ka2 = *(const float4*)&ska[8];
      float4 ka3 = *(const float4*)&ska[12];
      float4 kb0 = *(const float4*)&ska[16];
      float4 kb1 = *(const float4*)&ska[20];
      float4 kb2 = *(const float4*)&ska[24];
      float4 kb3 = *(const float4*)&ska[28];
      float sa = q0.x * ka0.x + q0.y * ka0.y + q0.z * ka0.z + q0.w * ka0.w
               + q1.x * ka1.x + q1.y * ka1.y + q1.z * ka1.z + q1.w * ka1.w
               + q2.x * ka2.x + q2.y * ka2.y + q2.z * ka2.z + q2.w * ka2.w
               + q3.x * ka3.x + q3.y * ka3.y + q3.z * ka3.z + q3.w * ka3.w;
      float sb = q0.x * kb0.x + q0.y * kb0.y + q0.z * kb0.z + q0.w * kb0.w
               + q1.x * kb1.x + q1.y * kb1.y + q1.z * kb1.z + q1.w * kb1.w
               + q2.x * kb2.x + q2.y * kb2.y + q2.z * kb2.z + q2.w * kb2.w
               + q3.x * kb3.x + q3.y * kb3.y + q3.z * kb3.z + q3.w * kb3.w;
      float pm = fmaxf(sa, sb);
      float dmx = pm - mmax;
      if (dmx > 8.f) {             // defer-rescale (T13), ~1-2 times total
        float scal = __expf(-dmx); // mmax may be -3.4e38: exp(-huge)=0, ok
        lsa *= scal; lsb *= scal;
        oa0.x *= scal; oa0.y *= scal; oa0.z *= scal; oa0.w *= scal;
        oa1.x *= scal; oa1.y *= scal; oa1.z *= scal; oa1.w *= scal;
        oa2.x *= scal; oa2.y *= scal; oa2.z *= scal; oa2.w *= scal;
        oa3.x *= scal; oa3.y *= scal; oa3.z *= scal; oa3.w *= scal;
        ob0.x *= scal; ob0.y *= scal; ob0.z *= scal; ob0.w *= scal;
        ob1.x *= scal; ob1.y *= scal; ob1.z *= scal; ob1.w *= scal;
        ob2.x *= scal; ob2.y *= scal; ob2.z *= scal; ob2.w *= scal;
        ob3.x *= scal; ob3.y *= scal; ob3.z *= scal; ob3.w *= scal;
        mmax = pm;
      }
      float ea = __expf(sa - mmax);
      float eb = __expf(sb - mmax);
      lsa += ea; lsb += eb;
      const float* sva = &sv[tt * 16];
      float4 va0 = *(const float4*)&sva[0];
      float4 va1 = *(const float4*)&sva[4];
      float4 va2 = *(const float4*)&sva[8];
      float4 va3 = *(const float4*)&sva[12];
      float4 vb0 = *(const float4*)&sva[16];
      float4 vb1 = *(const float4*)&sva[20];
      float4 vb2 = *(const float4*)&sva[24];
      float4 vb3 = *(const float4*)&sva[28];
      oa0.x += ea * va0.x; oa0.y += ea * va0.y; oa0.z += ea * va0.z; oa0.w += ea * va0.w;
      oa1.x += ea * va1.x; oa1.y += ea * va1.y; oa1.z += ea * va1.z; oa1.w += ea * va1.w;
      oa2.x += ea * va2.x; oa2.y += ea * va2.y; oa2.z += ea * va2.z; oa2.w += ea * va2.w;
      oa3.x += ea * va3.x; oa3.y += ea * va3.y; oa3.z += ea * va3.z; oa3.w += ea * va3.w;
      ob0.x += eb * vb0.x; ob0.y += eb * vb0.y; ob0.z += eb * vb0.z; ob0.w += eb * vb0.w;
      ob1.x += eb * vb1.x; ob1.y += eb * vb1.y; ob1.z += eb * vb1.z; ob1.w += eb * vb1.w;
      ob2.x += eb * vb2.x; ob2.y += eb * vb2.y; ob2.z += eb * vb2.z; ob2.w += eb * vb2.w;
      ob3.x += eb * vb3.x; ob3.y += eb * vb3.y; ob3.z += eb * vb3.z; ob3.w += eb * vb3.w;
    }
    float ri = 1.f / (lsa + lsb);
    float* ob = out + b * CNW + c * 96000 + gr * 16 + (m * 100 + t) * 96;
    float4 w0 = make_float4((oa0.x + ob0.x) * ri, (oa0.y + ob0.y) * ri,
                            (oa0.z + ob0.z) * ri, (oa0.w + ob0.w) * ri);
    float4 w1 = make_float4((oa1.x + ob1.x) * ri, (oa1.y + ob1.y) * ri,
                            (oa1.z + ob1.z) * ri, (oa1.w + ob1.w) * ri);
    float4 w2 = make_float4((oa2.x + ob2.x) * ri, (oa2.y + ob2.y) * ri,
                            (oa2.z + ob2.z) * ri, (oa2.w + ob2.w) * ri);
    float4 w3 = make_float4((oa3.x + ob3.x) * ri, (oa3.y + ob3.y) * ri,
                            (oa3.z + ob3.z) * ri, (oa3.w + ob3.w) * ri);
    *(float4*)&ob[0]  = w0;
    *(float4*)&ob[4]  = w1;
    *(float4*)&ob[8]  = w2;
    *(float4*)&ob[12] = w3;
  }
}

// ---------------- t = swapaxes(feat_attn,1,3) + x  (per (b,n) 96x96 tile) ----
__global__ __launch_bounds__(256) void trans_add_k(const float* __restrict__ z,
    const float* __restrict__ x, float* __restrict__ out) {
  __shared__ float ld[96 * 97];
  int b = blockIdx.x / 1000, n = blockIdx.x % 1000;
  int t = threadIdx.x;
  const float* zp = z + b * CNW + n * 96;
  for (int i = t; i < 9216; i += 256) {
    int r = i / 96, col = i % 96;
    ld[r * 97 + col] = zp[r * 96000 + col];
  }
  __syncthreads();
  const float* xp = x + b * CNW + n * 96;
  float* op = out + b * CNW + n * 96;
  for (int i = t; i < 9216; i += 256) {
    int cc = i / 96, ww = i % 96;
    op[cc * 96000 + ww] = ld[ww * 97 + cc] + xp[cc * 96000 + ww];
  }
}

// ---------------- GN stats: 12 contiguous (b,group) slices of 1.536M floats --
__global__ __launch_bounds__(256) void gnstats_k(const float* __restrict__ a,
                                                 float* __restrict__ st) {
  int slice = blockIdx.x >> 5, chunk = blockIdx.x & 31;
  const float4* p = (const float4*)(a + slice * 1536000 + chunk * 48000);
  float s = 0.f, q = 0.f;
  for (int i = threadIdx.x; i < 12000; i += 256) {
    float4 v = p[i];
    s += v.x + v.y + v.z + v.w;
    q += v.x * v.x + v.y * v.y + v.z * v.z + v.w * v.w;
  }
#pragma unroll
  for (int d = 32; d >= 1; d >>= 1) { s += __shfl_down(s, d, 64); q += __shfl_down(q, d, 64); }
  __shared__ float ls[4], lq[4];
  int wid = threadIdx.x >> 6;
  if ((threadIdx.x & 63) == 0) { ls[wid] = s; lq[wid] = q; }
  __syncthreads();
  if (threadIdx.x == 0) {
    atomicAdd(&st[slice * 2 + 0], ls[0] + ls[1] + ls[2] + ls[3]);
    atomicAdd(&st[slice * 2 + 1], lq[0] + lq[1] + lq[2] + lq[3]);
  }
}

// ---------------- out = relu( BN2(IN(l2)) + BNr(right_raw) ) -----------------
// stR is canonical per-(b,o) [384]; BN over both batches sums the two halves.
__global__ __launch_bounds__(256) void final_k(float* __restrict__ outp,
    const float* __restrict__ l2, const float* __restrict__ stR,
    const float* __restrict__ st2, const float* __restrict__ rw,
    const float* __restrict__ rb, const float* __restrict__ w2,
    const float* __restrict__ b2) {
  int stride = gridDim.x * 256;
  for (int i4 = blockIdx.x * 256 + threadIdx.x; i4 < 4608000; i4 += stride) {
    int i = i4 * 4;
    int b = i / CNW, o = (i / 96000) % 96;
    float mr = (stR[o * 2] + stR[192 + o * 2]) * (1.f / 192000.f);
    float vr = (stR[o * 2 + 1] + stR[192 + o * 2 + 1]) * (1.f / 192000.f) - mr * mr;
    float rs = rsqrtf(vr + EPSV) * rw[o];
    float rsh = rb[o] - mr * rs;
    const float inv = 1.f / 96000.f;
    float m0 = st2[o * 2] * inv,       v0 = st2[o * 2 + 1] * inv - m0 * m0;
    float m1 = st2[192 + o * 2] * inv, v1 = st2[192 + o * 2 + 1] * inv - m1 * m1;
    float bv = 0.5f * (v0 / (v0 + EPSV) + v1 / (v1 + EPSV));
    float ls = rsqrtf(bv + EPSV) * w2[o];
    float mi = b ? m1 : m0, vi = b ? v1 : v0;
    float lsc = rsqrtf(vi + EPSV) * ls;
    float lsh = b2[o] - mi * lsc;
    float4 R = ((float4*)outp)[i4];
    float4 L = ((const float4*)l2)[i4];
    float4 O;
    O.x = fmaxf(R.x * rs + rsh + L.x * lsc + lsh, 0.f);
    O.y = fmaxf(R.y * rs + rsh + L.y * lsc + lsh, 0.f);
    O.z = fmaxf(R.z * rs + rsh + L.z * lsc + lsh, 0.f);
    O.w = fmaxf(R.w * rs + rsh + L.w * lsc + lsh, 0.f);
    ((float4*)outp)[i4] = O;
  }
}

extern "C" void kernel_launch(void* const* d_in, const int* in_sizes, int n_in,
                              void* d_out, int out_size, void* d_ws, size_t ws_size,
                              hipStream_t stream) {
  const float* x        = (const float*)d_in[0];
  const float* w_linear = (const float*)d_in[1];
  const float* gn_w     = (const float*)d_in[2];
  const float* gn_b     = (const float*)d_in[3];
  const float* w_right  = (const float*)d_in[4];
  const float* b_right  = (const float*)d_in[5];
  const float* bn_r_w   = (const float*)d_in[6];
  const float* bn_r_b   = (const float*)d_in[7];
  const float* w_l1     = (const float*)d_in[8];
  const float* b_l1     = (const float*)d_in[9];
  const float* bn1_w    = (const float*)d_in[10];
  const float* bn1_b    = (const float*)d_in[11];
  const float* w_l2     = (const float*)d_in[12];
  const float* b_l2     = (const float*)d_in[13];
  const float* bn2_w    = (const float*)d_in[14];
  const float* bn2_b    = (const float*)d_in[15];
  float* out = (float*)d_out;

  float* A      = (float*)d_ws;         // 18,432,000 floats
  float* Bb     = A + TOT;              // 18,432,000 floats
  float* Pg     = Bb + TOT;             // 115,200 floats
  float* stGN   = Pg + 115200;          // 24
  float* stBNr  = stGN + 24;            // 384 canonical
  float* stIN1  = stBNr + 384;          // 384 canonical
  float* stIN2  = stIN1 + 384;          // 384 canonical
  float* rawBNr = stIN2 + 384;          // NREP*384
  float* rawIN1 = rawBNr + NREP * 384;  // NREP*384
  float* rawIN2 = rawIN1 + NREP * 384;  // NREP*384

  // zero stGN + canonical + all raw replica buffers
  hipMemsetAsync(stGN, 0, (24 + 3 * 384 + 3 * NREP * 384) * sizeof(float), stream);

  // feat = conv1x1(x, w_linear)  -> A
  conv_k<0, 0><<<2000, 256, 0, stream>>>(x, w_linear, nullptr, A,
                                         nullptr, nullptr, nullptr, nullptr);
  // block means + sinkhorn + top-3 cut -> P
  attnA_k<<<1152, 256, 0, stream>>>(A, Pg);
  // attention -> Bb ([B,C,N,W] layout)
  attnB_k<<<11520, 128, 0, stream>>>(A, Pg, Bb);
  // t = swapaxes(feat_attn,1,3) + x -> A
  trans_add_k<<<2000, 256, 0, stream>>>(Bb, x, A);
  // GN group stats
  gnstats_k<<<384, 256, 0, stream>>>(A, stGN);
  // right = conv(GN(y), w_right)+b -> d_out (raw), GN folded; replicated stats
  conv_k<1, 1><<<2000, 256, 0, stream>>>(A, w_right, b_right, out,
                                         stGN, gn_w, gn_b, rawBNr);
  // l1 = conv(GN(y), w_l1)+b -> Bb (raw), GN folded; replicated stats
  conv_k<1, 1><<<2000, 256, 0, stream>>>(A, w_l1, b_l1, Bb,
                                         stGN, gn_w, gn_b, rawIN1);
  // collapse replicas for BNr and IN1
  collapse_k<<<3, 256, 0, stream>>>(rawBNr, stBNr, rawIN1, stIN1);
  // l2 = conv(relu(BN1(IN(l1))), w_l2)+b -> A (raw), input fold; replicated stats
  conv_k<2, 1><<<2000, 256, 0, stream>>>(Bb, w_l2, b_l2, A,
                                         stIN1, bn1_w, bn1_b, rawIN2);
  // collapse replicas for IN2
  collapse_k<<<2, 256, 0, stream>>>(rawIN2, stIN2, nullptr, nullptr);
  // out = relu(BN2(IN(l2)) + BNr(right_raw))
  final_k<<<2048, 256, 0, stream>>>(out, A, stBNr, stIN2,
                                    bn_r_w, bn_r_b, bn2_w, bn2_b);
}

// Round 9
// 561.112 us; speedup vs baseline: 1.5134x; 1.1140x over previous
//
#include <hip/hip_runtime.h>
#include <math.h>

#define CNW 9216000      // C*N*W = 96*1000*96
#define TOT 18432000     // B*C*N*W
#define EPSV 1e-5f
#define ITEMP 0.10206207261596575f   // 1/sqrt(96)
#define NREP 16          // stats replicas (breaks same-address atomic chains)

typedef __attribute__((ext_vector_type(8))) short bf16x8;   // 8 bf16 = 4 VGPR
typedef __attribute__((ext_vector_type(4))) float f32x4;

union FragU { unsigned u[4]; bf16x8 v; };

// round-to-nearest-even fp32 -> bf16 (upper 16 bits)
__device__ __forceinline__ unsigned bfr(float x) {
  union { float f; unsigned u; } v; v.f = x;
  return (v.u + 0x7fffu + ((v.u >> 16) & 1u)) >> 16;
}

// =============== conv0: fp32 LDS conv (feeds the discrete sinkhorn cut; =====
// =============== kept fp32 so top-3 selection is not perturbed) ============
__global__ __launch_bounds__(256) void conv_k(const float* __restrict__ x,
    const float* __restrict__ w, float* __restrict__ out) {
  __shared__ float xt[96 * 100];
  __shared__ float wt[96 * 100];
  int b = blockIdx.x / 1000, n = blockIdx.x % 1000;
  int t = threadIdx.x;
  const float* xp = x + b * CNW + n * 96;
  for (int i = t; i < 9216; i += 256) {
    int cc = i / 96, j = i % 96;
    xt[cc * 100 + j] = xp[cc * 96000 + j];
    wt[cc * 100 + j] = w[i];            // wt[o][c] since i = o*96+c
  }
  __syncthreads();
  if (t < 192) {
    int wq = t % 24, og = t / 24;
    float4 acc[12];
#pragma unroll
    for (int oo = 0; oo < 12; ++oo) acc[oo] = make_float4(0.f, 0.f, 0.f, 0.f);
    for (int cq = 0; cq < 24; ++cq) {
      float4 xv0 = *(const float4*)&xt[(4 * cq + 0) * 100 + 4 * wq];
      float4 xv1 = *(const float4*)&xt[(4 * cq + 1) * 100 + 4 * wq];
      float4 xv2 = *(const float4*)&xt[(4 * cq + 2) * 100 + 4 * wq];
      float4 xv3 = *(const float4*)&xt[(4 * cq + 3) * 100 + 4 * wq];
#pragma unroll
      for (int oo = 0; oo < 12; ++oo) {
        int o = og * 12 + oo;
        float4 wv = *(const float4*)&wt[o * 100 + 4 * cq];
        acc[oo].x += wv.x * xv0.x + wv.y * xv1.x + wv.z * xv2.x + wv.w * xv3.x;
        acc[oo].y += wv.x * xv0.y + wv.y * xv1.y + wv.z * xv2.y + wv.w * xv3.y;
        acc[oo].z += wv.x * xv0.z + wv.y * xv1.z + wv.z * xv2.z + wv.w * xv3.z;
        acc[oo].w += wv.x * xv0.w + wv.y * xv1.w + wv.z * xv2.w + wv.w * xv3.w;
      }
    }
    float* op = out + b * CNW + n * 96 + 4 * wq;
#pragma unroll
    for (int oo = 0; oo < 12; ++oo) *(float4*)&op[(og * 12 + oo) * 96000] = acc[oo];
  }
}

// =============== prep kernels: pack weights into bf16 k-pair layout =========
// W2[o][c2] (49-u32 row pitch) : u32 = bf16(W[o][2c2]) | bf16(W[o][2c2+1])<<16
__global__ __launch_bounds__(256) void prep0_k(const float* __restrict__ w,
                                               unsigned* __restrict__ w2g) {
  int t = threadIdx.x;
  for (int i = t; i < 4704; i += 256) {
    int o = i / 49, c2 = i % 49;
    unsigned p = 0;
    if (c2 < 48) p = bfr(w[o * 96 + 2 * c2]) | (bfr(w[o * 96 + 2 * c2 + 1]) << 16);
    w2g[i] = p;
  }
}

// collapse GN replicas, fold GN scale into w_right/w_l1 (per b), exact bias2
__global__ __launch_bounds__(256) void prep_rl_k(const float* __restrict__ rawGN,
    const float* __restrict__ wR, const float* __restrict__ bR,
    const float* __restrict__ wL, const float* __restrict__ bL,
    const float* __restrict__ gnw, const float* __restrict__ gnb,
    unsigned* __restrict__ w2R, float* __restrict__ b2R,
    unsigned* __restrict__ w2L, float* __restrict__ b2L) {
  __shared__ float stGN[24];
  __shared__ float scl[2][96], sh[2][96];
  int t = threadIdx.x;
  if (t < 24) {
    float s = 0.f;
    for (int r = 0; r < NREP; ++r) s += rawGN[r * 24 + t];
    stGN[t] = s;
  }
  __syncthreads();
  if (t < 192) {
    int b = t / 96, c = t % 96, g = c >> 4;
    float m = stGN[b * 12 + g * 2] * (1.f / 1536000.f);
    float v = stGN[b * 12 + g * 2 + 1] * (1.f / 1536000.f) - m * m;
    float sc = rsqrtf(v + EPSV) * gnw[c];
    scl[b][c] = sc;
    sh[b][c] = gnb[c] - m * sc;
  }
  __syncthreads();
  for (int i = t; i < 2 * 2 * 4704; i += 256) {
    int wsel = i / 9408, rem = i % 9408, b = rem / 4704, j = rem % 4704;
    int o = j / 49, c2 = j % 49;
    const float* W = wsel ? wL : wR;
    unsigned p = 0;
    if (c2 < 48) {
      float w0 = W[o * 96 + 2 * c2] * scl[b][2 * c2];
      float w1 = W[o * 96 + 2 * c2 + 1] * scl[b][2 * c2 + 1];
      p = bfr(w0) | (bfr(w1) << 16);
    }
    (wsel ? w2L : w2R)[b * 4704 + j] = p;
  }
  for (int i = t; i < 2 * 2 * 96; i += 256) {
    int wsel = i / 192, rem = i % 192, b = rem / 96, o = rem % 96;
    const float* W = wsel ? wL : wR;
    float acc = (wsel ? bL : bR)[o];
    for (int c = 0; c < 96; ++c) acc += W[o * 96 + c] * sh[b][c];
    (wsel ? b2L : b2R)[b * 96 + o] = acc;
  }
}

// collapse IN1 replicas, compute BN1(IN) affine, pack w_l2 (unscaled)
__global__ __launch_bounds__(256) void prep_l2_k(const float* __restrict__ rawIN1,
    const float* __restrict__ w, const float* __restrict__ bi,
    const float* __restrict__ bn1w, const float* __restrict__ bn1b,
    unsigned* __restrict__ w2g, float* __restrict__ b2g,
    float* __restrict__ sclg, float* __restrict__ shfg) {
  __shared__ float st[384];
  int t = threadIdx.x;
  for (int i = t; i < 384; i += 256) {
    float s = 0.f;
    for (int r = 0; r < NREP; ++r) s += rawIN1[r * 384 + i];
    st[i] = s;
  }
  __syncthreads();
  if (t < 192) {
    int b = t / 96, c = t % 96;
    const float inv = 1.f / 96000.f;
    float m0 = st[c * 2] * inv, v0 = st[c * 2 + 1] * inv - m0 * m0;
    float m1 = st[192 + c * 2] * inv, v1 = st[192 + c * 2 + 1] * inv - m1 * m1;
    float bv = 0.5f * (v0 / (v0 + EPSV) + v1 / (v1 + EPSV));
    float bscale = rsqrtf(bv + EPSV) * bn1w[c];
    float mi = b ? m1 : m0, vi = b ? v1 : v0;
    float sc = rsqrtf(vi + EPSV) * bscale;
    sclg[t] = sc;
    shfg[t] = bn1b[c] - mi * sc;
    b2g[t] = bi[c];
  }
  for (int i = t; i < 4704; i += 256) {
    int o = i / 49, c2 = i % 49;
    unsigned p = 0;
    if (c2 < 48) p = bfr(w[o * 96 + 2 * c2]) | (bfr(w[o * 96 + 2 * c2 + 1]) << 16);
    w2g[i] = p;
  }
}

// =============== MFMA conv: D[o,nw] = W[96x96] @ X[96x96000] per batch ======
// MODE 1: pre-scaled per-b weights (GN fold). MODE 2: x' = relu(x*scl+shf).
// Block: 96x64 output tile, 4 waves x 6 M-tiles, K=3 steps of 32 (16x16x32).
// k-pair u32 layout, 49-u32 row pitch (stride%32==17 words -> <=2-way banks).
template <int MODE, int STATS>
__global__ __launch_bounds__(256) void convm_k(const float* __restrict__ xin,
    const unsigned* __restrict__ w2g, const float* __restrict__ b2g,
    const float* __restrict__ sclg, const float* __restrict__ shfg,
    float* __restrict__ outp, float* __restrict__ st_out) {
  __shared__ __align__(16) unsigned ldsW[96 * 49];
  __shared__ __align__(16) unsigned xt2[64 * 49];
  __shared__ float ldsB[96], lS[96], lH[96];
  __shared__ float ssum[4 * 96], sqsum[4 * 96];
  int tile = blockIdx.x % 1500, b = blockIdx.x / 1500;
  int nw0 = tile * 64;
  int t = threadIdx.x;
  // W2 + per-channel params
  const unsigned* wsrc = w2g + (MODE == 1 ? b * 4704 : 0);
  for (int i = t; i < 1176; i += 256)
    ((float4*)ldsW)[i] = ((const float4*)wsrc)[i];
  if (t < 96) {
    ldsB[t] = (MODE == 0) ? 0.f : b2g[b * 96 + t];
    if (MODE == 2) { lS[t] = sclg[b * 96 + t]; lH[t] = shfg[b * 96 + t]; }
  }
  __syncthreads();
  // stage x tile transposed as k-pairs: xt2[nw][c2]
  const float* xb = xin + b * CNW + nw0;
  for (int i = t; i < 768; i += 256) {
    int c2 = i >> 4, j4 = i & 15;
    const float* r0 = xb + (2 * c2) * 96000 + j4 * 4;
    float4 x0 = *(const float4*)r0;
    float4 x1 = *(const float4*)(r0 + 96000);
    if (MODE == 2) {
      float s0 = lS[2 * c2], h0 = lH[2 * c2];
      float s1 = lS[2 * c2 + 1], h1 = lH[2 * c2 + 1];
      x0.x = fmaxf(x0.x * s0 + h0, 0.f); x0.y = fmaxf(x0.y * s0 + h0, 0.f);
      x0.z = fmaxf(x0.z * s0 + h0, 0.f); x0.w = fmaxf(x0.w * s0 + h0, 0.f);
      x1.x = fmaxf(x1.x * s1 + h1, 0.f); x1.y = fmaxf(x1.y * s1 + h1, 0.f);
      x1.z = fmaxf(x1.z * s1 + h1, 0.f); x1.w = fmaxf(x1.w * s1 + h1, 0.f);
    }
    int base = j4 * 4;
    xt2[(base + 0) * 49 + c2] = bfr(x0.x) | (bfr(x1.x) << 16);
    xt2[(base + 1) * 49 + c2] = bfr(x0.y) | (bfr(x1.y) << 16);
    xt2[(base + 2) * 49 + c2] = bfr(x0.z) | (bfr(x1.z) << 16);
    xt2[(base + 3) * 49 + c2] = bfr(x0.w) | (bfr(x1.w) << 16);
  }
  __syncthreads();
  int lane = t & 63, nt = t >> 6;
  int l15 = lane & 15, kg = lane >> 4;
  f32x4 acc[6];
#pragma unroll
  for (int mt = 0; mt < 6; ++mt) acc[mt] = (f32x4){0.f, 0.f, 0.f, 0.f};
#pragma unroll
  for (int ks = 0; ks < 3; ++ks) {
    int cb = ks * 16 + kg * 4;          // c2 base for this lane's k-group
    FragU bf;
    int brow = (nt * 16 + l15) * 49 + cb;
    bf.u[0] = xt2[brow + 0]; bf.u[1] = xt2[brow + 1];
    bf.u[2] = xt2[brow + 2]; bf.u[3] = xt2[brow + 3];
#pragma unroll
    for (int mt = 0; mt < 6; ++mt) {
      FragU af;
      int arow = (mt * 16 + l15) * 49 + cb;
      af.u[0] = ldsW[arow + 0]; af.u[1] = ldsW[arow + 1];
      af.u[2] = ldsW[arow + 2]; af.u[3] = ldsW[arow + 3];
      acc[mt] = __builtin_amdgcn_mfma_f32_16x16x32_bf16(af.v, bf.v, acc[mt], 0, 0, 0);
    }
  }
  // epilogue: C/D layout col=lane&15 (nw), row=(lane>>4)*4+reg (o)  [m89]
  float* ob = outp + b * CNW + nw0 + nt * 16 + l15;
  float sv[6][4], qv[6][4];
#pragma unroll
  for (int mt = 0; mt < 6; ++mt)
#pragma unroll
    for (int r = 0; r < 4; ++r) {
      int o = mt * 16 + kg * 4 + r;
      float val = acc[mt][r] + ldsB[o];
      ob[o * 96000] = val;
      if (STATS) { sv[mt][r] = val; qv[mt][r] = val * val; }
    }
  if (STATS) {
#pragma unroll
    for (int msk = 1; msk <= 8; msk <<= 1)
#pragma unroll
      for (int mt = 0; mt < 6; ++mt)
#pragma unroll
        for (int r = 0; r < 4; ++r) {
          sv[mt][r] += __shfl_xor(sv[mt][r], msk, 64);
          qv[mt][r] += __shfl_xor(qv[mt][r], msk, 64);
        }
    if (l15 == 0)
#pragma unroll
      for (int mt = 0; mt < 6; ++mt)
#pragma unroll
        for (int r = 0; r < 4; ++r) {
          int o = mt * 16 + kg * 4 + r;
          ssum[nt * 96 + o] = sv[mt][r];
          sqsum[nt * 96 + o] = qv[mt][r];
        }
    __syncthreads();
    if (t < 96) {
      float S = ssum[t] + ssum[96 + t] + ssum[192 + t] + ssum[288 + t];
      float Q = sqsum[t] + sqsum[96 + t] + sqsum[192 + t] + sqsum[288 + t];
      float* dst = st_out + (tile & (NREP - 1)) * 384 + b * 192 + t * 2;
      atomicAdd(dst + 0, S);
      atomicAdd(dst + 1, Q);
    }
  }
}

// ---------------- collapse NREP replicas -> canonical [384] -----------------
__global__ __launch_bounds__(256) void collapse_k(const float* __restrict__ r0,
    float* __restrict__ o0, const float* __restrict__ r1, float* __restrict__ o1) {
  int t = blockIdx.x * 256 + threadIdx.x;
  const float* r = (t < 384) ? r0 : r1;
  float* o = (t < 384) ? o0 : o1;
  int i = (t < 384) ? t : t - 384;
  if (t < 768 && r) {
    float s = 0.f;
#pragma unroll
    for (int k = 0; k < NREP; ++k) s += r[k * 384 + i];
    o[i] = s;
  }
}

// ---------------- attention kernel A: block means -> sinkhorn -> top3 cut ---
__global__ __launch_bounds__(256) void attnA_k(const float* __restrict__ feat,
                                               float* __restrict__ Pg) {
  int head = blockIdx.x;
  int b = head / 576, rem = head % 576, c = rem / 6, gr = rem % 6;
  const float* fb = feat + b * CNW + c * 96000 + gr * 16;
  __shared__ float qm[160];
  __shared__ float L[110];
  int t = threadIdx.x;
  if (t < 160) {
    int m = t / 16, j = t % 16;
    float s = 0.f;
    for (int ss = 0; ss < 100; ++ss) s += fb[(m * 100 + ss) * 96 + j];
    qm[m * 16 + j] = s * 0.01f;
  }
  __syncthreads();
  if (t < 100) {
    int m = t / 10, n2 = t % 10;
    float acc = 0.f;
#pragma unroll
    for (int j = 0; j < 16; ++j) acc += qm[m * 16 + j] * qm[n2 * 16 + j];
    L[m * 11 + n2] = acc * ITEMP;
  }
  __syncthreads();
  for (int it = 0; it < 8; ++it) {
    if (t < 10) {
      float mx = -3.4e38f;
      for (int n2 = 0; n2 < 10; ++n2) mx = fmaxf(mx, L[t * 11 + n2]);
      float s = 0.f;
      for (int n2 = 0; n2 < 10; ++n2) s += expf(L[t * 11 + n2] - mx);
      float lse = mx + logf(s);
      for (int n2 = 0; n2 < 10; ++n2) L[t * 11 + n2] -= lse;
    }
    __syncthreads();
    if (t < 10) {
      float mx = -3.4e38f;
      for (int m = 0; m < 10; ++m) mx = fmaxf(mx, L[m * 11 + t]);
      float s = 0.f;
      for (int m = 0; m < 10; ++m) s += expf(L[m * 11 + t] - mx);
      float lse = mx + logf(s);
      for (int m = 0; m < 10; ++m) L[m * 11 + t] -= lse;
    }
    __syncthreads();
  }
  if (t < 10) {
    float p[10];
#pragma unroll
    for (int n2 = 0; n2 < 10; ++n2) p[n2] = expf(L[t * 11 + n2]);
    int i1 = -1, i2 = -1;
    float m1 = -1.f, m2 = -1.f, m3 = -1.f;
#pragma unroll
    for (int n2 = 0; n2 < 10; ++n2) if (p[n2] > m1) { m1 = p[n2]; i1 = n2; }
#pragma unroll
    for (int n2 = 0; n2 < 10; ++n2) if (n2 != i1 && p[n2] > m2) { m2 = p[n2]; i2 = n2; }
#pragma unroll
    for (int n2 = 0; n2 < 10; ++n2) if (n2 != i1 && n2 != i2 && p[n2] > m3) m3 = p[n2];
#pragma unroll
    for (int n2 = 0; n2 < 10; ++n2)
      Pg[head * 100 + t * 10 + n2] = (p[n2] >= m3) ? p[n2] : 0.f;
  }
}

// ---------------- attention kernel B (flash-style, ILP-2 over keys) ---------
__global__ __launch_bounds__(128) void attnB_k(const float* __restrict__ feat,
    const float* __restrict__ Pg, float* __restrict__ out) {
  int m = blockIdx.x % 10;
  int head = blockIdx.x / 10;
  int b = head / 576, rem = head % 576, c = rem / 6, gr = rem % 6;
  const float* fb = feat + b * CNW + c * 96000 + gr * 16;
  __shared__ float sk[100 * 16];
  __shared__ float sv[100 * 16];
  int t = threadIdx.x;
  float p[10];
#pragma unroll
  for (int n2 = 0; n2 < 10; ++n2) p[n2] = Pg[head * 100 + m * 10 + n2];
  for (int i4 = t; i4 < 400; i4 += 128) {
    int s = i4 >> 2, q = i4 & 3;
    float4 ak = make_float4(0.f, 0.f, 0.f, 0.f);
    float4 av = make_float4(0.f, 0.f, 0.f, 0.f);
#pragma unroll
    for (int n2 = 0; n2 < 10; ++n2) {
      if (p[n2] != 0.f) {
        float4 kv = *(const float4*)&fb[(n2 * 100 + s) * 96 + 4 * q];
        float pe = p[n2];
        ak.x += pe * kv.x; ak.y += pe * kv.y; ak.z += pe * kv.z; ak.w += pe * kv.w;
        float ex = fmaxf(kv.x, 0.f) + __expf(fminf(kv.x, 0.f)) - 1.f;
        float ey = fmaxf(kv.y, 0.f) + __expf(fminf(kv.y, 0.f)) - 1.f;
        float ez = fmaxf(kv.z, 0.f) + __expf(fminf(kv.z, 0.f)) - 1.f;
        float ew = fmaxf(kv.w, 0.f) + __expf(fminf(kv.w, 0.f)) - 1.f;
        av.x += pe * ex; av.y += pe * ey; av.z += pe * ez; av.w += pe * ew;
      }
    }
    *(float4*)&sk[s * 16 + 4 * q] = ak;
    *(float4*)&sv[s * 16 + 4 * q] = av;
  }
  __syncthreads();
  if (t < 100) {
    const float* qp = &fb[(m * 100 + t) * 96];
    float4 q0 = *(const float4*)&qp[0];
    float4 q1 = *(const float4*)&qp[4];
    float4 q2 = *(const float4*)&qp[8];
    float4 q3 = *(const float4*)&qp[12];
    q0.x *= ITEMP; q0.y *= ITEMP; q0.z *= ITEMP; q0.w *= ITEMP;
    q1.x *= ITEMP; q1.y *= ITEMP; q1.z *= ITEMP; q1.w *= ITEMP;
    q2.x *= ITEMP; q2.y *= ITEMP; q2.z *= ITEMP; q2.w *= ITEMP;
    q3.x *= ITEMP; q3.y *= ITEMP; q3.z *= ITEMP; q3.w *= ITEMP;
    float4 z4 = make_float4(0.f, 0.f, 0.f, 0.f);
    float4 oa0 = z4, oa1 = z4, oa2 = z4, oa3 = z4;
    float4 ob0 = z4, ob1 = z4, ob2 = z4, ob3 = z4;
    float mmax = -3.4e38f, lsa = 0.f, lsb = 0.f;
    for (int tt = 0; tt < 100; tt += 2) {
      const float* ska = &sk[tt * 16];
      float4 ka0 = *(const float4*)&ska[0];
      float4 ka1 = *(const float4*)&ska[4];
      float4 ka2 = *(const float4*)&ska[8];
      float4 ka3 = *(const float4*)&ska[12];
      float4 kb0 = *(const float4*)&ska[16];
      float4 kb1 = *(const float4*)&ska[20];
      float4 kb2 = *(const float4*)&ska[24];
      float4 kb3 = *(const float4*)&ska[28];
      float sa = q0.x * ka0.x + q0.y * ka0.y + q0.z * ka0.z + q0.w * ka0.w
               + q1.x * ka1.x + q1.y * ka1.y + q1.z * ka1.z + q1.w * ka1.w
               + q2.x * ka2.x + q2.y * ka2.y + q2.z * ka2.z + q2.w * ka2.w
               + q3.x * ka3.x + q3.y * ka3.y + q3.z * ka3.z + q3.w * ka3.w;
      float sb = q0.x * kb0.x + q0.y * kb0.y + q0.z * kb0.z + q0.w * kb0.w
               + q1.x * kb1.x + q1.y * kb1.y + q1.z * kb1.z + q1.w * kb1.w
               + q2.x * kb2.x + q2.y * kb2.y + q2.z * kb2.z + q2.w * kb2.w
               + q3.x * kb3.x + q3.y * kb3.y + q3.z * kb3.z + q3.w * kb3.w;
      float pm = fmaxf(sa, sb);
      float dmx = pm - mmax;
      if (dmx > 8.f) {
        float scal = __expf(-dmx);
        lsa *= scal; lsb *= scal;
        oa0.x *= scal; oa0.y *= scal; oa0.z *= scal; oa0.w *= scal;
        oa1.x *= scal; oa1.y *= scal; oa1.z *= scal; oa1.w *= scal;
        oa2.x *= scal; oa2.y *= scal; oa2.z *= scal; oa2.w *= scal;
        oa3.x *= scal; oa3.y *= scal; oa3.z *= scal; oa3.w *= scal;
        ob0.x *= scal; ob0.y *= scal; ob0.z *= scal; ob0.w *= scal;
        ob1.x *= scal; ob1.y *= scal; ob1.z *= scal; ob1.w *= scal;
        ob2.x *= scal; ob2.y *= scal; ob2.z *= scal; ob2.w *= scal;
        ob3.x *= scal; ob3.y *= scal; ob3.z *= scal; ob3.w *= scal;
        mmax = pm;
      }
      float ea = __expf(sa - mmax);
      float eb = __expf(sb - mmax);
      lsa += ea; lsb += eb;
      const float* sva = &sv[tt * 16];
      float4 va0 = *(const float4*)&sva[0];
      float4 va1 = *(const float4*)&sva[4];
      float4 va2 = *(const float4*)&sva[8];
      float4 va3 = *(const float4*)&sva[12];
      float4 vb0 = *(const float4*)&sva[16];
      float4 vb1 = *(const float4*)&sva[20];
      float4 vb2 = *(const float4*)&sva[24];
      float4 vb3 = *(const float4*)&sva[28];
      oa0.x += ea * va0.x; oa0.y += ea * va0.y; oa0.z += ea * va0.z; oa0.w += ea * va0.w;
      oa1.x += ea * va1.x; oa1.y += ea * va1.y; oa1.z += ea * va1.z; oa1.w += ea * va1.w;
      oa2.x += ea * va2.x; oa2.y += ea * va2.y; oa2.z += ea * va2.z; oa2.w += ea * va2.w;
      oa3.x += ea * va3.x; oa3.y += ea * va3.y; oa3.z += ea * va3.z; oa3.w += ea * va3.w;
      ob0.x += eb * vb0.x; ob0.y += eb * vb0.y; ob0.z += eb * vb0.z; ob0.w += eb * vb0.w;
      ob1.x += eb * vb1.x; ob1.y += eb * vb1.y; ob1.z += eb * vb1.z; ob1.w += eb * vb1.w;
      ob2.x += eb * vb2.x; ob2.y += eb * vb2.y; ob2.z += eb * vb2.z; ob2.w += eb * vb2.w;
      ob3.x += eb * vb3.x; ob3.y += eb * vb3.y; ob3.z += eb * vb3.z; ob3.w += eb * vb3.w;
    }
    float ri = 1.f / (lsa + lsb);
    float* ob = out + b * CNW + c * 96000 + gr * 16 + (m * 100 + t) * 96;
    float4 w0 = make_float4((oa0.x + ob0.x) * ri, (oa0.y + ob0.y) * ri,
                            (oa0.z + ob0.z) * ri, (oa0.w + ob0.w) * ri);
    float4 w1 = make_float4((oa1.x + ob1.x) * ri, (oa1.y + ob1.y) * ri,
                            (oa1.z + ob1.z) * ri, (oa1.w + ob1.w) * ri);
    float4 w2 = make_float4((oa2.x + ob2.x) * ri, (oa2.y + ob2.y) * ri,
                            (oa2.z + ob2.z) * ri, (oa2.w + ob2.w) * ri);
    float4 w3 = make_float4((oa3.x + ob3.x) * ri, (oa3.y + ob3.y) * ri,
                            (oa3.z + ob3.z) * ri, (oa3.w + ob3.w) * ri);
    *(float4*)&ob[0]  = w0;
    *(float4*)&ob[4]  = w1;
    *(float4*)&ob[8]  = w2;
    *(float4*)&ob[12] = w3;
  }
}

// ------ t = swapaxes(feat_attn,1,3) + x, with fused GN stats ---------------
// g = k/6 is exact under the 36-iter unroll (256*6=1536 = group stride),
// so per-group register accumulators are statically indexed (rule #20 safe).
__global__ __launch_bounds__(256) void trans_add_k(const float* __restrict__ z,
    const float* __restrict__ x, float* __restrict__ out,
    float* __restrict__ rawGN) {
  __shared__ float ld[96 * 97];
  __shared__ float red[4 * 12];
  int b = blockIdx.x / 1000, n = blockIdx.x % 1000;
  int t = threadIdx.x;
  const float* zp = z + b * CNW + n * 96;
  for (int i = t; i < 9216; i += 256) {
    int r = i / 96, col = i % 96;
    ld[r * 97 + col] = zp[r * 96000 + col];
  }
  __syncthreads();
  const float* xp = x + b * CNW + n * 96;
  float* op = out + b * CNW + n * 96;
  float sg[6], qg[6];
#pragma unroll
  for (int g = 0; g < 6; ++g) { sg[g] = 0.f; qg[g] = 0.f; }
#pragma unroll
  for (int k = 0; k < 36; ++k) {
    int i = t + k * 256;
    int g = k / 6;                    // compile-time under unroll
    int cc = i / 96, ww = i % 96;
    float val = ld[ww * 97 + cc] + xp[cc * 96000 + ww];
    op[cc * 96000 + ww] = val;
    sg[g] += val;
    qg[g] += val * val;
  }
#pragma unroll
  for (int msk = 1; msk <= 32; msk <<= 1)
#pragma unroll
    for (int g = 0; g < 6; ++g) {
      sg[g] += __shfl_xor(sg[g], msk, 64);
      qg[g] += __shfl_xor(qg[g], msk, 64);
    }
  int wid = t >> 6;
  if ((t & 63) == 0)
#pragma unroll
    for (int g = 0; g < 6; ++g) {
      red[wid * 12 + g * 2 + 0] = sg[g];
      red[wid * 12 + g * 2 + 1] = qg[g];
    }
  __syncthreads();
  if (t < 12) {
    float s = red[t] + red[12 + t] + red[24 + t] + red[36 + t];
    atomicAdd(&rawGN[(n & (NREP - 1)) * 24 + b * 12 + t], s);
  }
}

// ---------------- out = relu( BN2(IN(l2)) + BNr(right_raw) ) -----------------
__global__ __launch_bounds__(256) void final_k(float* __restrict__ outp,
    const float* __restrict__ l2, const float* __restrict__ stR,
    const float* __restrict__ st2, const float* __restrict__ rw,
    const float* __restrict__ rb, const float* __restrict__ w2,
    const float* __restrict__ b2) {
  int stride = gridDim.x * 256;
  for (int i4 = blockIdx.x * 256 + threadIdx.x; i4 < 4608000; i4 += stride) {
    int i = i4 * 4;
    int b = i / CNW, o = (i / 96000) % 96;
    float mr = (stR[o * 2] + stR[192 + o * 2]) * (1.f / 192000.f);
    float vr = (stR[o * 2 + 1] + stR[192 + o * 2 + 1]) * (1.f / 192000.f) - mr * mr;
    float rs = rsqrtf(vr + EPSV) * rw[o];
    float rsh = rb[o] - mr * rs;
    const float inv = 1.f / 96000.f;
    float m0 = st2[o * 2] * inv,       v0 = st2[o * 2 + 1] * inv - m0 * m0;
    float m1 = st2[192 + o * 2] * inv, v1 = st2[192 + o * 2 + 1] * inv - m1 * m1;
    float bv = 0.5f * (v0 / (v0 + EPSV) + v1 / (v1 + EPSV));
    float ls = rsqrtf(bv + EPSV) * w2[o];
    float mi = b ? m1 : m0, vi = b ? v1 : v0;
    float lsc = rsqrtf(vi + EPSV) * ls;
    float lsh = b2[o] - mi * lsc;
    float4 R = ((float4*)outp)[i4];
    float4 L = ((const float4*)l2)[i4];
    float4 O;
    O.x = fmaxf(R.x * rs + rsh + L.x * lsc + lsh, 0.f);
    O.y = fmaxf(R.y * rs + rsh + L.y * lsc + lsh, 0.f);
    O.z = fmaxf(R.z * rs + rsh + L.z * lsc + lsh, 0.f);
    O.w = fmaxf(R.w * rs + rsh + L.w * lsc + lsh, 0.f);
    ((float4*)outp)[i4] = O;
  }
}

extern "C" void kernel_launch(void* const* d_in, const int* in_sizes, int n_in,
                              void* d_out, int out_size, void* d_ws, size_t ws_size,
                              hipStream_t stream) {
  const float* x        = (const float*)d_in[0];
  const float* w_linear = (const float*)d_in[1];
  const float* gn_w     = (const float*)d_in[2];
  const float* gn_b     = (const float*)d_in[3];
  const float* w_right  = (const float*)d_in[4];
  const float* b_right  = (const float*)d_in[5];
  const float* bn_r_w   = (const float*)d_in[6];
  const float* bn_r_b   = (const float*)d_in[7];
  const float* w_l1     = (const float*)d_in[8];
  const float* b_l1     = (const float*)d_in[9];
  const float* bn1_w    = (const float*)d_in[10];
  const float* bn1_b    = (const float*)d_in[11];
  const float* w_l2     = (const float*)d_in[12];
  const float* b_l2     = (const float*)d_in[13];
  const float* bn2_w    = (const float*)d_in[14];
  const float* bn2_b    = (const float*)d_in[15];
  float* out = (float*)d_out;

  float* A      = (float*)d_ws;            // TOT
  float* Bb     = A + TOT;                 // TOT
  float* Pg     = Bb + TOT;                // 115200
  float* rawGN  = Pg + 115200;             // NREP*24 = 384
  float* rawBNr = rawGN + NREP * 24;       // NREP*384
  float* rawIN1 = rawBNr + NREP * 384;     // NREP*384
  float* rawIN2 = rawIN1 + NREP * 384;     // NREP*384
  float* stBNr  = rawIN2 + NREP * 384;     // 384
  float* stIN2  = stBNr + 384;             // 384
  unsigned* w2_0  = (unsigned*)(stIN2 + 384);  // 4704
  unsigned* w2R   = w2_0 + 4704;               // 2*4704
  unsigned* w2L   = w2R + 2 * 4704;            // 2*4704
  unsigned* w2l2  = w2L + 2 * 4704;            // 4704
  float* b2R   = (float*)(w2l2 + 4704);        // 192
  float* b2L   = b2R + 192;                    // 192
  float* b2l2  = b2L + 192;                    // 192
  float* scl1g = b2l2 + 192;                   // 192
  float* shf1g = scl1g + 192;                  // 192

  // zero all replicated stats buffers (rawGN..rawIN2 contiguous)
  hipMemsetAsync(rawGN, 0, (NREP * 24 + 3 * NREP * 384) * sizeof(float), stream);

  // pack w_linear (bf16 k-pairs) — no stats dependency
  prep0_k<<<1, 256, 0, stream>>>(w_linear, w2_0);
  // feat = conv1x1(x, w_linear) -> A   [fp32: protects the sinkhorn top-3 cut]
  conv_k<<<2000, 256, 0, stream>>>(x, w_linear, A);
  // block means + sinkhorn + top-3 cut -> P
  attnA_k<<<1152, 256, 0, stream>>>(A, Pg);
  // attention -> Bb
  attnB_k<<<11520, 128, 0, stream>>>(A, Pg, Bb);
  // t = swapaxes(feat_attn,1,3) + x -> A ; fused GN stats -> rawGN replicas
  trans_add_k<<<2000, 256, 0, stream>>>(Bb, x, A, rawGN);
  // collapse GN + fold GN into w_right/w_l1 (bf16 pack) + exact bias2
  prep_rl_k<<<1, 256, 0, stream>>>(rawGN, w_right, b_right, w_l1, b_l1,
                                   gn_w, gn_b, w2R, b2R, w2L, b2L);
  // right = MFMA conv -> d_out (raw); replicated BN stats
  convm_k<1, 1><<<3000, 256, 0, stream>>>(A, w2R, b2R, nullptr, nullptr,
                                          out, rawBNr);
  // l1 = MFMA conv -> Bb (raw); replicated IN stats
  convm_k<1, 1><<<3000, 256, 0, stream>>>(A, w2L, b2L, nullptr, nullptr,
                                          Bb, rawIN1);
  // collapse IN1 + BN1(IN) affine + pack w_l2
  prep_l2_k<<<1, 256, 0, stream>>>(rawIN1, w_l2, b_l2, bn1_w, bn1_b,
                                   w2l2, b2l2, scl1g, shf1g);
  // l2 = MFMA conv of relu(l1*scl+shf) -> A (raw); replicated IN stats
  convm_k<2, 1><<<3000, 256, 0, stream>>>(Bb, w2l2, b2l2, scl1g, shf1g,
                                          A, rawIN2);
  // collapse BNr and IN2 replicas
  collapse_k<<<3, 256, 0, stream>>>(rawBNr, stBNr, rawIN2, stIN2);
  // out = relu(BN2(IN(l2)) + BNr(right_raw))
  final_k<<<2048, 256, 0, stream>>>(out, A, stBNr, stIN2,
                                    bn_r_w, bn_r_b, bn2_w, bn2_b);
}

// Round 10
// 543.240 us; speedup vs baseline: 1.5632x; 1.0329x over previous
//
#include <hip/hip_runtime.h>
#include <math.h>

#define CNW 9216000      // C*N*W = 96*1000*96
#define TOT 18432000     // B*C*N*W
#define EPSV 1e-5f
#define ITEMP 0.10206207261596575f   // 1/sqrt(96)
#define NREP 16          // stats replicas (breaks same-address atomic chains)

typedef __attribute__((ext_vector_type(8))) short bf16x8;   // 8 bf16 = 4 VGPR
typedef __attribute__((ext_vector_type(4))) float f32x4;
typedef __attribute__((ext_vector_type(2))) float f32x2;    // v_pk_* packed pair

union FragU { unsigned u[4]; bf16x8 v; };
union V4 { float4 f4; f32x2 h[2]; };

// round-to-nearest-even fp32 -> bf16 (upper 16 bits)
__device__ __forceinline__ unsigned bfr(float x) {
  union { float f; unsigned u; } v; v.f = x;
  return (v.u + 0x7fffu + ((v.u >> 16) & 1u)) >> 16;
}

// =============== conv0: fp32 LDS conv (feeds the discrete sinkhorn cut; =====
// =============== kept fp32 so top-3 selection is not perturbed) ============
__global__ __launch_bounds__(256) void conv_k(const float* __restrict__ x,
    const float* __restrict__ w, float* __restrict__ out) {
  __shared__ float xt[96 * 100];
  __shared__ float wt[96 * 100];
  int b = blockIdx.x / 1000, n = blockIdx.x % 1000;
  int t = threadIdx.x;
  const float* xp = x + b * CNW + n * 96;
  for (int i = t; i < 9216; i += 256) {
    int cc = i / 96, j = i % 96;
    xt[cc * 100 + j] = xp[cc * 96000 + j];
    wt[cc * 100 + j] = w[i];            // wt[o][c] since i = o*96+c
  }
  __syncthreads();
  if (t < 192) {
    int wq = t % 24, og = t / 24;
    float4 acc[12];
#pragma unroll
    for (int oo = 0; oo < 12; ++oo) acc[oo] = make_float4(0.f, 0.f, 0.f, 0.f);
    for (int cq = 0; cq < 24; ++cq) {
      float4 xv0 = *(const float4*)&xt[(4 * cq + 0) * 100 + 4 * wq];
      float4 xv1 = *(const float4*)&xt[(4 * cq + 1) * 100 + 4 * wq];
      float4 xv2 = *(const float4*)&xt[(4 * cq + 2) * 100 + 4 * wq];
      float4 xv3 = *(const float4*)&xt[(4 * cq + 3) * 100 + 4 * wq];
#pragma unroll
      for (int oo = 0; oo < 12; ++oo) {
        int o = og * 12 + oo;
        float4 wv = *(const float4*)&wt[o * 100 + 4 * cq];
        acc[oo].x += wv.x * xv0.x + wv.y * xv1.x + wv.z * xv2.x + wv.w * xv3.x;
        acc[oo].y += wv.x * xv0.y + wv.y * xv1.y + wv.z * xv2.y + wv.w * xv3.y;
        acc[oo].z += wv.x * xv0.z + wv.y * xv1.z + wv.z * xv2.z + wv.w * xv3.z;
        acc[oo].w += wv.x * xv0.w + wv.y * xv1.w + wv.z * xv2.w + wv.w * xv3.w;
      }
    }
    float* op = out + b * CNW + n * 96 + 4 * wq;
#pragma unroll
    for (int oo = 0; oo < 12; ++oo) *(float4*)&op[(og * 12 + oo) * 96000] = acc[oo];
  }
}

// =============== prep kernels: pack weights into bf16 k-pair layout =========
__global__ __launch_bounds__(256) void prep0_k(const float* __restrict__ w,
                                               unsigned* __restrict__ w2g) {
  int t = threadIdx.x;
  for (int i = t; i < 4704; i += 256) {
    int o = i / 49, c2 = i % 49;
    unsigned p = 0;
    if (c2 < 48) p = bfr(w[o * 96 + 2 * c2]) | (bfr(w[o * 96 + 2 * c2 + 1]) << 16);
    w2g[i] = p;
  }
}

// collapse GN replicas, fold GN scale into w_right/w_l1 (per b), exact bias2
__global__ __launch_bounds__(256) void prep_rl_k(const float* __restrict__ rawGN,
    const float* __restrict__ wR, const float* __restrict__ bR,
    const float* __restrict__ wL, const float* __restrict__ bL,
    const float* __restrict__ gnw, const float* __restrict__ gnb,
    unsigned* __restrict__ w2R, float* __restrict__ b2R,
    unsigned* __restrict__ w2L, float* __restrict__ b2L) {
  __shared__ float stGN[24];
  __shared__ float scl[2][96], sh[2][96];
  int t = threadIdx.x;
  if (t < 24) {
    float s = 0.f;
    for (int r = 0; r < NREP; ++r) s += rawGN[r * 24 + t];
    stGN[t] = s;
  }
  __syncthreads();
  if (t < 192) {
    int b = t / 96, c = t % 96, g = c >> 4;
    float m = stGN[b * 12 + g * 2] * (1.f / 1536000.f);
    float v = stGN[b * 12 + g * 2 + 1] * (1.f / 1536000.f) - m * m;
    float sc = rsqrtf(v + EPSV) * gnw[c];
    scl[b][c] = sc;
    sh[b][c] = gnb[c] - m * sc;
  }
  __syncthreads();
  for (int i = t; i < 2 * 2 * 4704; i += 256) {
    int wsel = i / 9408, rem = i % 9408, b = rem / 4704, j = rem % 4704;
    int o = j / 49, c2 = j % 49;
    const float* W = wsel ? wL : wR;
    unsigned p = 0;
    if (c2 < 48) {
      float w0 = W[o * 96 + 2 * c2] * scl[b][2 * c2];
      float w1 = W[o * 96 + 2 * c2 + 1] * scl[b][2 * c2 + 1];
      p = bfr(w0) | (bfr(w1) << 16);
    }
    (wsel ? w2L : w2R)[b * 4704 + j] = p;
  }
  for (int i = t; i < 2 * 2 * 96; i += 256) {
    int wsel = i / 192, rem = i % 192, b = rem / 96, o = rem % 96;
    const float* W = wsel ? wL : wR;
    float acc = (wsel ? bL : bR)[o];
    for (int c = 0; c < 96; ++c) acc += W[o * 96 + c] * sh[b][c];
    (wsel ? b2L : b2R)[b * 96 + o] = acc;
  }
}

// collapse IN1 replicas, compute BN1(IN) affine, pack w_l2 (unscaled)
__global__ __launch_bounds__(256) void prep_l2_k(const float* __restrict__ rawIN1,
    const float* __restrict__ w, const float* __restrict__ bi,
    const float* __restrict__ bn1w, const float* __restrict__ bn1b,
    unsigned* __restrict__ w2g, float* __restrict__ b2g,
    float* __restrict__ sclg, float* __restrict__ shfg) {
  __shared__ float st[384];
  int t = threadIdx.x;
  for (int i = t; i < 384; i += 256) {
    float s = 0.f;
    for (int r = 0; r < NREP; ++r) s += rawIN1[r * 384 + i];
    st[i] = s;
  }
  __syncthreads();
  if (t < 192) {
    int b = t / 96, c = t % 96;
    const float inv = 1.f / 96000.f;
    float m0 = st[c * 2] * inv, v0 = st[c * 2 + 1] * inv - m0 * m0;
    float m1 = st[192 + c * 2] * inv, v1 = st[192 + c * 2 + 1] * inv - m1 * m1;
    float bv = 0.5f * (v0 / (v0 + EPSV) + v1 / (v1 + EPSV));
    float bscale = rsqrtf(bv + EPSV) * bn1w[c];
    float mi = b ? m1 : m0, vi = b ? v1 : v0;
    float sc = rsqrtf(vi + EPSV) * bscale;
    sclg[t] = sc;
    shfg[t] = bn1b[c] - mi * sc;
    b2g[t] = bi[c];
  }
  for (int i = t; i < 4704; i += 256) {
    int o = i / 49, c2 = i % 49;
    unsigned p = 0;
    if (c2 < 48) p = bfr(w[o * 96 + 2 * c2]) | (bfr(w[o * 96 + 2 * c2 + 1]) << 16);
    w2g[i] = p;
  }
}

// =============== MFMA conv: D[o,nw] = W[96x96] @ X[96x96000] per batch ======
template <int MODE, int STATS>
__global__ __launch_bounds__(256) void convm_k(const float* __restrict__ xin,
    const unsigned* __restrict__ w2g, const float* __restrict__ b2g,
    const float* __restrict__ sclg, const float* __restrict__ shfg,
    float* __restrict__ outp, float* __restrict__ st_out) {
  __shared__ __align__(16) unsigned ldsW[96 * 49];
  __shared__ __align__(16) unsigned xt2[64 * 49];
  __shared__ float ldsB[96], lS[96], lH[96];
  __shared__ float ssum[4 * 96], sqsum[4 * 96];
  int tile = blockIdx.x % 1500, b = blockIdx.x / 1500;
  int nw0 = tile * 64;
  int t = threadIdx.x;
  const unsigned* wsrc = w2g + (MODE == 1 ? b * 4704 : 0);
  for (int i = t; i < 1176; i += 256)
    ((float4*)ldsW)[i] = ((const float4*)wsrc)[i];
  if (t < 96) {
    ldsB[t] = (MODE == 0) ? 0.f : b2g[b * 96 + t];
    if (MODE == 2) { lS[t] = sclg[b * 96 + t]; lH[t] = shfg[b * 96 + t]; }
  }
  __syncthreads();
  const float* xb = xin + b * CNW + nw0;
  for (int i = t; i < 768; i += 256) {
    int c2 = i >> 4, j4 = i & 15;
    const float* r0 = xb + (2 * c2) * 96000 + j4 * 4;
    float4 x0 = *(const float4*)r0;
    float4 x1 = *(const float4*)(r0 + 96000);
    if (MODE == 2) {
      float s0 = lS[2 * c2], h0 = lH[2 * c2];
      float s1 = lS[2 * c2 + 1], h1 = lH[2 * c2 + 1];
      x0.x = fmaxf(x0.x * s0 + h0, 0.f); x0.y = fmaxf(x0.y * s0 + h0, 0.f);
      x0.z = fmaxf(x0.z * s0 + h0, 0.f); x0.w = fmaxf(x0.w * s0 + h0, 0.f);
      x1.x = fmaxf(x1.x * s1 + h1, 0.f); x1.y = fmaxf(x1.y * s1 + h1, 0.f);
      x1.z = fmaxf(x1.z * s1 + h1, 0.f); x1.w = fmaxf(x1.w * s1 + h1, 0.f);
    }
    int base = j4 * 4;
    xt2[(base + 0) * 49 + c2] = bfr(x0.x) | (bfr(x1.x) << 16);
    xt2[(base + 1) * 49 + c2] = bfr(x0.y) | (bfr(x1.y) << 16);
    xt2[(base + 2) * 49 + c2] = bfr(x0.z) | (bfr(x1.z) << 16);
    xt2[(base + 3) * 49 + c2] = bfr(x0.w) | (bfr(x1.w) << 16);
  }
  __syncthreads();
  int lane = t & 63, nt = t >> 6;
  int l15 = lane & 15, kg = lane >> 4;
  f32x4 acc[6];
#pragma unroll
  for (int mt = 0; mt < 6; ++mt) acc[mt] = (f32x4){0.f, 0.f, 0.f, 0.f};
#pragma unroll
  for (int ks = 0; ks < 3; ++ks) {
    int cb = ks * 16 + kg * 4;
    FragU bf;
    int brow = (nt * 16 + l15) * 49 + cb;
    bf.u[0] = xt2[brow + 0]; bf.u[1] = xt2[brow + 1];
    bf.u[2] = xt2[brow + 2]; bf.u[3] = xt2[brow + 3];
#pragma unroll
    for (int mt = 0; mt < 6; ++mt) {
      FragU af;
      int arow = (mt * 16 + l15) * 49 + cb;
      af.u[0] = ldsW[arow + 0]; af.u[1] = ldsW[arow + 1];
      af.u[2] = ldsW[arow + 2]; af.u[3] = ldsW[arow + 3];
      acc[mt] = __builtin_amdgcn_mfma_f32_16x16x32_bf16(af.v, bf.v, acc[mt], 0, 0, 0);
    }
  }
  float* ob = outp + b * CNW + nw0 + nt * 16 + l15;
  float sv[6][4], qv[6][4];
#pragma unroll
  for (int mt = 0; mt < 6; ++mt)
#pragma unroll
    for (int r = 0; r < 4; ++r) {
      int o = mt * 16 + kg * 4 + r;
      float val = acc[mt][r] + ldsB[o];
      ob[o * 96000] = val;
      if (STATS) { sv[mt][r] = val; qv[mt][r] = val * val; }
    }
  if (STATS) {
#pragma unroll
    for (int msk = 1; msk <= 8; msk <<= 1)
#pragma unroll
      for (int mt = 0; mt < 6; ++mt)
#pragma unroll
        for (int r = 0; r < 4; ++r) {
          sv[mt][r] += __shfl_xor(sv[mt][r], msk, 64);
          qv[mt][r] += __shfl_xor(qv[mt][r], msk, 64);
        }
    if (l15 == 0)
#pragma unroll
      for (int mt = 0; mt < 6; ++mt)
#pragma unroll
        for (int r = 0; r < 4; ++r) {
          int o = mt * 16 + kg * 4 + r;
          ssum[nt * 96 + o] = sv[mt][r];
          sqsum[nt * 96 + o] = qv[mt][r];
        }
    __syncthreads();
    if (t < 96) {
      float S = ssum[t] + ssum[96 + t] + ssum[192 + t] + ssum[288 + t];
      float Q = sqsum[t] + sqsum[96 + t] + sqsum[192 + t] + sqsum[288 + t];
      float* dst = st_out + (tile & (NREP - 1)) * 384 + b * 192 + t * 2;
      atomicAdd(dst + 0, S);
      atomicAdd(dst + 1, Q);
    }
  }
}

// ---------------- collapse NREP replicas -> canonical [384] -----------------
__global__ __launch_bounds__(256) void collapse_k(const float* __restrict__ r0,
    float* __restrict__ o0, const float* __restrict__ r1, float* __restrict__ o1) {
  int t = blockIdx.x * 256 + threadIdx.x;
  const float* r = (t < 384) ? r0 : r1;
  float* o = (t < 384) ? o0 : o1;
  int i = (t < 384) ? t : t - 384;
  if (t < 768 && r) {
    float s = 0.f;
#pragma unroll
    for (int k = 0; k < NREP; ++k) s += r[k * 384 + i];
    o[i] = s;
  }
}

// ---------------- attention kernel A: block means -> sinkhorn -> top3 cut ---
__global__ __launch_bounds__(256) void attnA_k(const float* __restrict__ feat,
                                               float* __restrict__ Pg) {
  int head = blockIdx.x;
  int b = head / 576, rem = head % 576, c = rem / 6, gr = rem % 6;
  const float* fb = feat + b * CNW + c * 96000 + gr * 16;
  __shared__ float qm[160];
  __shared__ float L[110];
  int t = threadIdx.x;
  if (t < 160) {
    int m = t / 16, j = t % 16;
    float s = 0.f;
    for (int ss = 0; ss < 100; ++ss) s += fb[(m * 100 + ss) * 96 + j];
    qm[m * 16 + j] = s * 0.01f;
  }
  __syncthreads();
  if (t < 100) {
    int m = t / 10, n2 = t % 10;
    float acc = 0.f;
#pragma unroll
    for (int j = 0; j < 16; ++j) acc += qm[m * 16 + j] * qm[n2 * 16 + j];
    L[m * 11 + n2] = acc * ITEMP;
  }
  __syncthreads();
  for (int it = 0; it < 8; ++it) {
    if (t < 10) {
      float mx = -3.4e38f;
      for (int n2 = 0; n2 < 10; ++n2) mx = fmaxf(mx, L[t * 11 + n2]);
      float s = 0.f;
      for (int n2 = 0; n2 < 10; ++n2) s += expf(L[t * 11 + n2] - mx);
      float lse = mx + logf(s);
      for (int n2 = 0; n2 < 10; ++n2) L[t * 11 + n2] -= lse;
    }
    __syncthreads();
    if (t < 10) {
      float mx = -3.4e38f;
      for (int m = 0; m < 10; ++m) mx = fmaxf(mx, L[m * 11 + t]);
      float s = 0.f;
      for (int m = 0; m < 10; ++m) s += expf(L[m * 11 + t] - mx);
      float lse = mx + logf(s);
      for (int m = 0; m < 10; ++m) L[m * 11 + t] -= lse;
    }
    __syncthreads();
  }
  if (t < 10) {
    float p[10];
#pragma unroll
    for (int n2 = 0; n2 < 10; ++n2) p[n2] = expf(L[t * 11 + n2]);
    int i1 = -1, i2 = -1;
    float m1 = -1.f, m2 = -1.f, m3 = -1.f;
#pragma unroll
    for (int n2 = 0; n2 < 10; ++n2) if (p[n2] > m1) { m1 = p[n2]; i1 = n2; }
#pragma unroll
    for (int n2 = 0; n2 < 10; ++n2) if (n2 != i1 && p[n2] > m2) { m2 = p[n2]; i2 = n2; }
#pragma unroll
    for (int n2 = 0; n2 < 10; ++n2) if (n2 != i1 && n2 != i2 && p[n2] > m3) m3 = p[n2];
#pragma unroll
    for (int n2 = 0; n2 < 10; ++n2)
      Pg[head * 100 + t * 10 + n2] = (p[n2] >= m3) ? p[n2] : 0.f;
  }
}

// ---------------- attention kernel B (flash-style, packed-FP32 pairs) -------
// phase-2 dot products and PV accumulate as f32x2 (v_pk_fma_f32 on gfx950's
// packed-FP32 pipe): 16 pk_fma + ~12 scalar ops per 2-key iter vs 72 scalar.
__global__ __launch_bounds__(128) void attnB_k(const float* __restrict__ feat,
    const float* __restrict__ Pg, float* __restrict__ out) {
  int m = blockIdx.x % 10;
  int head = blockIdx.x / 10;
  int b = head / 576, rem = head % 576, c = rem / 6, gr = rem % 6;
  const float* fb = feat + b * CNW + c * 96000 + gr * 16;
  __shared__ float sk[100 * 16];
  __shared__ float sv[100 * 16];
  int t = threadIdx.x;
  float p[10];
#pragma unroll
  for (int n2 = 0; n2 < 10; ++n2) p[n2] = Pg[head * 100 + m * 10 + n2];
  // build mixed sk/sv (v = elu(k), branchless)
  for (int i4 = t; i4 < 400; i4 += 128) {
    int s = i4 >> 2, q = i4 & 3;
    float4 ak = make_float4(0.f, 0.f, 0.f, 0.f);
    float4 av = make_float4(0.f, 0.f, 0.f, 0.f);
#pragma unroll
    for (int n2 = 0; n2 < 10; ++n2) {
      if (p[n2] != 0.f) {
        float4 kv = *(const float4*)&fb[(n2 * 100 + s) * 96 + 4 * q];
        float pe = p[n2];
        ak.x += pe * kv.x; ak.y += pe * kv.y; ak.z += pe * kv.z; ak.w += pe * kv.w;
        float ex = fmaxf(kv.x, 0.f) + __expf(fminf(kv.x, 0.f)) - 1.f;
        float ey = fmaxf(kv.y, 0.f) + __expf(fminf(kv.y, 0.f)) - 1.f;
        float ez = fmaxf(kv.z, 0.f) + __expf(fminf(kv.z, 0.f)) - 1.f;
        float ew = fmaxf(kv.w, 0.f) + __expf(fminf(kv.w, 0.f)) - 1.f;
        av.x += pe * ex; av.y += pe * ey; av.z += pe * ez; av.w += pe * ew;
      }
    }
    *(float4*)&sk[s * 16 + 4 * q] = ak;
    *(float4*)&sv[s * 16 + 4 * q] = av;
  }
  __syncthreads();
  if (t < 100) {
    const float* qp = &fb[(m * 100 + t) * 96];
    V4 qv0, qv1, qv2, qv3;
    qv0.f4 = *(const float4*)&qp[0];
    qv1.f4 = *(const float4*)&qp[4];
    qv2.f4 = *(const float4*)&qp[8];
    qv3.f4 = *(const float4*)&qp[12];
    f32x2 q2[8];
    q2[0] = qv0.h[0] * ITEMP; q2[1] = qv0.h[1] * ITEMP;
    q2[2] = qv1.h[0] * ITEMP; q2[3] = qv1.h[1] * ITEMP;
    q2[4] = qv2.h[0] * ITEMP; q2[5] = qv2.h[1] * ITEMP;
    q2[6] = qv3.h[0] * ITEMP; q2[7] = qv3.h[1] * ITEMP;
    f32x2 o2a[8], o2b[8];
#pragma unroll
    for (int j = 0; j < 8; ++j) { o2a[j] = (f32x2){0.f, 0.f}; o2b[j] = (f32x2){0.f, 0.f}; }
    float mmax = -3.4e38f, lsa = 0.f, lsb = 0.f;
    for (int tt = 0; tt < 100; tt += 2) {
      const float* ska = &sk[tt * 16];
      V4 ka0, ka1, ka2, ka3, kb0, kb1, kb2, kb3;
      ka0.f4 = *(const float4*)&ska[0];
      ka1.f4 = *(const float4*)&ska[4];
      ka2.f4 = *(const float4*)&ska[8];
      ka3.f4 = *(const float4*)&ska[12];
      kb0.f4 = *(const float4*)&ska[16];
      kb1.f4 = *(const float4*)&ska[20];
      kb2.f4 = *(const float4*)&ska[24];
      kb3.f4 = *(const float4*)&ska[28];
      // packed dot products: 8 pk ops per key, 2 independent chains
      f32x2 aa = q2[0] * ka0.h[0];
      f32x2 ab = q2[0] * kb0.h[0];
      aa = q2[1] * ka0.h[1] + aa;  ab = q2[1] * kb0.h[1] + ab;
      aa = q2[2] * ka1.h[0] + aa;  ab = q2[2] * kb1.h[0] + ab;
      aa = q2[3] * ka1.h[1] + aa;  ab = q2[3] * kb1.h[1] + ab;
      aa = q2[4] * ka2.h[0] + aa;  ab = q2[4] * kb2.h[0] + ab;
      aa = q2[5] * ka2.h[1] + aa;  ab = q2[5] * kb2.h[1] + ab;
      aa = q2[6] * ka3.h[0] + aa;  ab = q2[6] * kb3.h[0] + ab;
      aa = q2[7] * ka3.h[1] + aa;  ab = q2[7] * kb3.h[1] + ab;
      float sa = aa.x + aa.y;
      float sb = ab.x + ab.y;
      float pm = fmaxf(sa, sb);
      float dmx = pm - mmax;
      if (dmx > 8.f) {             // defer-rescale (T13), ~1-2 times total
        float scal = __expf(-dmx); // mmax may be -3.4e38: exp(-huge)=0, ok
        lsa *= scal; lsb *= scal;
#pragma unroll
        for (int j = 0; j < 8; ++j) { o2a[j] *= scal; o2b[j] *= scal; }
        mmax = pm;
      }
      float ea = __expf(sa - mmax);
      float eb = __expf(sb - mmax);
      lsa += ea; lsb += eb;
      f32x2 e2a = (f32x2){ea, ea};
      f32x2 e2b = (f32x2){eb, eb};
      const float* sva = &sv[tt * 16];
      V4 va0, va1, va2, va3, vb0, vb1, vb2, vb3;
      va0.f4 = *(const float4*)&sva[0];
      va1.f4 = *(const float4*)&sva[4];
      va2.f4 = *(const float4*)&sva[8];
      va3.f4 = *(const float4*)&sva[12];
      vb0.f4 = *(const float4*)&sva[16];
      vb1.f4 = *(const float4*)&sva[20];
      vb2.f4 = *(const float4*)&sva[24];
      vb3.f4 = *(const float4*)&sva[28];
      o2a[0] = e2a * va0.h[0] + o2a[0];  o2b[0] = e2b * vb0.h[0] + o2b[0];
      o2a[1] = e2a * va0.h[1] + o2a[1];  o2b[1] = e2b * vb0.h[1] + o2b[1];
      o2a[2] = e2a * va1.h[0] + o2a[2];  o2b[2] = e2b * vb1.h[0] + o2b[2];
      o2a[3] = e2a * va1.h[1] + o2a[3];  o2b[3] = e2b * vb1.h[1] + o2b[3];
      o2a[4] = e2a * va2.h[0] + o2a[4];  o2b[4] = e2b * vb2.h[0] + o2b[4];
      o2a[5] = e2a * va2.h[1] + o2a[5];  o2b[5] = e2b * vb2.h[1] + o2b[5];
      o2a[6] = e2a * va3.h[0] + o2a[6];  o2b[6] = e2b * vb3.h[0] + o2b[6];
      o2a[7] = e2a * va3.h[1] + o2a[7];  o2b[7] = e2b * vb3.h[1] + o2b[7];
    }
    float ri = 1.f / (lsa + lsb);
    float* ob = out + b * CNW + c * 96000 + gr * 16 + (m * 100 + t) * 96;
    V4 w0, w1, w2, w3;
    w0.h[0] = (o2a[0] + o2b[0]) * ri;  w0.h[1] = (o2a[1] + o2b[1]) * ri;
    w1.h[0] = (o2a[2] + o2b[2]) * ri;  w1.h[1] = (o2a[3] + o2b[3]) * ri;
    w2.h[0] = (o2a[4] + o2b[4]) * ri;  w2.h[1] = (o2a[5] + o2b[5]) * ri;
    w3.h[0] = (o2a[6] + o2b[6]) * ri;  w3.h[1] = (o2a[7] + o2b[7]) * ri;
    *(float4*)&ob[0]  = w0.f4;
    *(float4*)&ob[4]  = w1.f4;
    *(float4*)&ob[8]  = w2.f4;
    *(float4*)&ob[12] = w3.f4;
  }
}

// ------ t = swapaxes(feat_attn,1,3) + x, with fused GN stats ---------------
__global__ __launch_bounds__(256) void trans_add_k(const float* __restrict__ z,
    const float* __restrict__ x, float* __restrict__ out,
    float* __restrict__ rawGN) {
  __shared__ float ld[96 * 97];
  __shared__ float red[4 * 12];
  int b = blockIdx.x / 1000, n = blockIdx.x % 1000;
  int t = threadIdx.x;
  const float* zp = z + b * CNW + n * 96;
  for (int i = t; i < 9216; i += 256) {
    int r = i / 96, col = i % 96;
    ld[r * 97 + col] = zp[r * 96000 + col];
  }
  __syncthreads();
  const float* xp = x + b * CNW + n * 96;
  float* op = out + b * CNW + n * 96;
  float sg[6], qg[6];
#pragma unroll
  for (int g = 0; g < 6; ++g) { sg[g] = 0.f; qg[g] = 0.f; }
#pragma unroll
  for (int k = 0; k < 36; ++k) {
    int i = t + k * 256;
    int g = k / 6;                    // compile-time under unroll
    int cc = i / 96, ww = i % 96;
    float val = ld[ww * 97 + cc] + xp[cc * 96000 + ww];
    op[cc * 96000 + ww] = val;
    sg[g] += val;
    qg[g] += val * val;
  }
#pragma unroll
  for (int msk = 1; msk <= 32; msk <<= 1)
#pragma unroll
    for (int g = 0; g < 6; ++g) {
      sg[g] += __shfl_xor(sg[g], msk, 64);
      qg[g] += __shfl_xor(qg[g], msk, 64);
    }
  int wid = t >> 6;
  if ((t & 63) == 0)
#pragma unroll
    for (int g = 0; g < 6; ++g) {
      red[wid * 12 + g * 2 + 0] = sg[g];
      red[wid * 12 + g * 2 + 1] = qg[g];
    }
  __syncthreads();
  if (t < 12) {
    float s = red[t] + red[12 + t] + red[24 + t] + red[36 + t];
    atomicAdd(&rawGN[(n & (NREP - 1)) * 24 + b * 12 + t], s);
  }
}

// ---------------- out = relu( BN2(IN(l2)) + BNr(right_raw) ) -----------------
__global__ __launch_bounds__(256) void final_k(float* __restrict__ outp,
    const float* __restrict__ l2, const float* __restrict__ stR,
    const float* __restrict__ st2, const float* __restrict__ rw,
    const float* __restrict__ rb, const float* __restrict__ w2,
    const float* __restrict__ b2) {
  int stride = gridDim.x * 256;
  for (int i4 = blockIdx.x * 256 + threadIdx.x; i4 < 4608000; i4 += stride) {
    int i = i4 * 4;
    int b = i / CNW, o = (i / 96000) % 96;
    float mr = (stR[o * 2] + stR[192 + o * 2]) * (1.f / 192000.f);
    float vr = (stR[o * 2 + 1] + stR[192 + o * 2 + 1]) * (1.f / 192000.f) - mr * mr;
    float rs = rsqrtf(vr + EPSV) * rw[o];
    float rsh = rb[o] - mr * rs;
    const float inv = 1.f / 96000.f;
    float m0 = st2[o * 2] * inv,       v0 = st2[o * 2 + 1] * inv - m0 * m0;
    float m1 = st2[192 + o * 2] * inv, v1 = st2[192 + o * 2 + 1] * inv - m1 * m1;
    float bv = 0.5f * (v0 / (v0 + EPSV) + v1 / (v1 + EPSV));
    float ls = rsqrtf(bv + EPSV) * w2[o];
    float mi = b ? m1 : m0, vi = b ? v1 : v0;
    float lsc = rsqrtf(vi + EPSV) * ls;
    float lsh = b2[o] - mi * lsc;
    float4 R = ((float4*)outp)[i4];
    float4 L = ((const float4*)l2)[i4];
    float4 O;
    O.x = fmaxf(R.x * rs + rsh + L.x * lsc + lsh, 0.f);
    O.y = fmaxf(R.y * rs + rsh + L.y * lsc + lsh, 0.f);
    O.z = fmaxf(R.z * rs + rsh + L.z * lsc + lsh, 0.f);
    O.w = fmaxf(R.w * rs + rsh + L.w * lsc + lsh, 0.f);
    ((float4*)outp)[i4] = O;
  }
}

extern "C" void kernel_launch(void* const* d_in, const int* in_sizes, int n_in,
                              void* d_out, int out_size, void* d_ws, size_t ws_size,
                              hipStream_t stream) {
  const float* x        = (const float*)d_in[0];
  const float* w_linear = (const float*)d_in[1];
  const float* gn_w     = (const float*)d_in[2];
  const float* gn_b     = (const float*)d_in[3];
  const float* w_right  = (const float*)d_in[4];
  const float* b_right  = (const float*)d_in[5];
  const float* bn_r_w   = (const float*)d_in[6];
  const float* bn_r_b   = (const float*)d_in[7];
  const float* w_l1     = (const float*)d_in[8];
  const float* b_l1     = (const float*)d_in[9];
  const float* bn1_w    = (const float*)d_in[10];
  const float* bn1_b    = (const float*)d_in[11];
  const float* w_l2     = (const float*)d_in[12];
  const float* b_l2     = (const float*)d_in[13];
  const float* bn2_w    = (const float*)d_in[14];
  const float* bn2_b    = (const float*)d_in[15];
  float* out = (float*)d_out;

  float* A      = (float*)d_ws;            // TOT
  float* Bb     = A + TOT;                 // TOT
  float* Pg     = Bb + TOT;                // 115200
  float* rawGN  = Pg + 115200;             // NREP*24 = 384
  float* rawBNr = rawGN + NREP * 24;       // NREP*384
  float* rawIN1 = rawBNr + NREP * 384;     // NREP*384
  float* rawIN2 = rawIN1 + NREP * 384;     // NREP*384
  float* stBNr  = rawIN2 + NREP * 384;     // 384
  float* stIN2  = stBNr + 384;             // 384
  unsigned* w2_0  = (unsigned*)(stIN2 + 384);  // 4704
  unsigned* w2R   = w2_0 + 4704;               // 2*4704
  unsigned* w2L   = w2R + 2 * 4704;            // 2*4704
  unsigned* w2l2  = w2L + 2 * 4704;            // 4704
  float* b2R   = (float*)(w2l2 + 4704);        // 192
  float* b2L   = b2R + 192;                    // 192
  float* b2l2  = b2L + 192;                    // 192
  float* scl1g = b2l2 + 192;                   // 192
  float* shf1g = scl1g + 192;                  // 192

  hipMemsetAsync(rawGN, 0, (NREP * 24 + 3 * NREP * 384) * sizeof(float), stream);

  prep0_k<<<1, 256, 0, stream>>>(w_linear, w2_0);
  // feat = conv1x1(x, w_linear) -> A   [fp32: protects the sinkhorn top-3 cut]
  conv_k<<<2000, 256, 0, stream>>>(x, w_linear, A);
  attnA_k<<<1152, 256, 0, stream>>>(A, Pg);
  attnB_k<<<11520, 128, 0, stream>>>(A, Pg, Bb);
  trans_add_k<<<2000, 256, 0, stream>>>(Bb, x, A, rawGN);
  prep_rl_k<<<1, 256, 0, stream>>>(rawGN, w_right, b_right, w_l1, b_l1,
                                   gn_w, gn_b, w2R, b2R, w2L, b2L);
  convm_k<1, 1><<<3000, 256, 0, stream>>>(A, w2R, b2R, nullptr, nullptr,
                                          out, rawBNr);
  convm_k<1, 1><<<3000, 256, 0, stream>>>(A, w2L, b2L, nullptr, nullptr,
                                          Bb, rawIN1);
  prep_l2_k<<<1, 256, 0, stream>>>(rawIN1, w_l2, b_l2, bn1_w, bn1_b,
                                   w2l2, b2l2, scl1g, shf1g);
  convm_k<2, 1><<<3000, 256, 0, stream>>>(Bb, w2l2, b2l2, scl1g, shf1g,
                                          A, rawIN2);
  collapse_k<<<3, 256, 0, stream>>>(rawBNr, stBNr, rawIN2, stIN2);
  final_k<<<2048, 256, 0, stream>>>(out, A, stBNr, stIN2,
                                    bn_r_w, bn_r_b, bn2_w, bn2_b);
}

// Round 11
// 541.110 us; speedup vs baseline: 1.5693x; 1.0039x over previous
//
#include <hip/hip_runtime.h>
#include <math.h>

#define CNW 9216000      // C*N*W = 96*1000*96
#define TOT 18432000     // B*C*N*W
#define EPSV 1e-5f
#define ITEMP 0.10206207261596575f   // 1/sqrt(96)
#define NREP 16          // stats replicas (breaks same-address atomic chains)

typedef __attribute__((ext_vector_type(8))) short bf16x8;   // 8 bf16 = 4 VGPR
typedef __attribute__((ext_vector_type(4))) float f32x4;

union FragU { unsigned u[4]; bf16x8 v; };

// round-to-nearest-even fp32 -> bf16 (upper 16 bits)
__device__ __forceinline__ unsigned bfr(float x) {
  union { float f; unsigned u; } v; v.f = x;
  return (v.u + 0x7fffu + ((v.u >> 16) & 1u)) >> 16;
}

// =============== conv0: fp32 LDS conv (feeds the discrete sinkhorn cut; =====
// =============== kept fp32 so top-3 selection is not perturbed) ============
__global__ __launch_bounds__(256) void conv_k(const float* __restrict__ x,
    const float* __restrict__ w, float* __restrict__ out) {
  __shared__ float xt[96 * 100];
  __shared__ float wt[96 * 100];
  int b = blockIdx.x / 1000, n = blockIdx.x % 1000;
  int t = threadIdx.x;
  const float* xp = x + b * CNW + n * 96;
  for (int i = t; i < 9216; i += 256) {
    int cc = i / 96, j = i % 96;
    xt[cc * 100 + j] = xp[cc * 96000 + j];
    wt[cc * 100 + j] = w[i];            // wt[o][c] since i = o*96+c
  }
  __syncthreads();
  if (t < 192) {
    int wq = t % 24, og = t / 24;
    float4 acc[12];
#pragma unroll
    for (int oo = 0; oo < 12; ++oo) acc[oo] = make_float4(0.f, 0.f, 0.f, 0.f);
    for (int cq = 0; cq < 24; ++cq) {
      float4 xv0 = *(const float4*)&xt[(4 * cq + 0) * 100 + 4 * wq];
      float4 xv1 = *(const float4*)&xt[(4 * cq + 1) * 100 + 4 * wq];
      float4 xv2 = *(const float4*)&xt[(4 * cq + 2) * 100 + 4 * wq];
      float4 xv3 = *(const float4*)&xt[(4 * cq + 3) * 100 + 4 * wq];
#pragma unroll
      for (int oo = 0; oo < 12; ++oo) {
        int o = og * 12 + oo;
        float4 wv = *(const float4*)&wt[o * 100 + 4 * cq];
        acc[oo].x += wv.x * xv0.x + wv.y * xv1.x + wv.z * xv2.x + wv.w * xv3.x;
        acc[oo].y += wv.x * xv0.y + wv.y * xv1.y + wv.z * xv2.y + wv.w * xv3.y;
        acc[oo].z += wv.x * xv0.z + wv.y * xv1.z + wv.z * xv2.z + wv.w * xv3.z;
        acc[oo].w += wv.x * xv0.w + wv.y * xv1.w + wv.z * xv2.w + wv.w * xv3.w;
      }
    }
    float* op = out + b * CNW + n * 96 + 4 * wq;
#pragma unroll
    for (int oo = 0; oo < 12; ++oo) *(float4*)&op[(og * 12 + oo) * 96000] = acc[oo];
  }
}

// =============== prep kernels: pack weights into bf16 k-pair layout =========
__global__ __launch_bounds__(256) void prep0_k(const float* __restrict__ w,
                                               unsigned* __restrict__ w2g) {
  int t = threadIdx.x;
  for (int i = t; i < 4704; i += 256) {
    int o = i / 49, c2 = i % 49;
    unsigned p = 0;
    if (c2 < 48) p = bfr(w[o * 96 + 2 * c2]) | (bfr(w[o * 96 + 2 * c2 + 1]) << 16);
    w2g[i] = p;
  }
}

// collapse GN replicas, fold GN scale into w_right/w_l1 (per b), exact bias2
__global__ __launch_bounds__(256) void prep_rl_k(const float* __restrict__ rawGN,
    const float* __restrict__ wR, const float* __restrict__ bR,
    const float* __restrict__ wL, const float* __restrict__ bL,
    const float* __restrict__ gnw, const float* __restrict__ gnb,
    unsigned* __restrict__ w2R, float* __restrict__ b2R,
    unsigned* __restrict__ w2L, float* __restrict__ b2L) {
  __shared__ float stGN[24];
  __shared__ float scl[2][96], sh[2][96];
  int t = threadIdx.x;
  if (t < 24) {
    float s = 0.f;
    for (int r = 0; r < NREP; ++r) s += rawGN[r * 24 + t];
    stGN[t] = s;
  }
  __syncthreads();
  if (t < 192) {
    int b = t / 96, c = t % 96, g = c >> 4;
    float m = stGN[b * 12 + g * 2] * (1.f / 1536000.f);
    float v = stGN[b * 12 + g * 2 + 1] * (1.f / 1536000.f) - m * m;
    float sc = rsqrtf(v + EPSV) * gnw[c];
    scl[b][c] = sc;
    sh[b][c] = gnb[c] - m * sc;
  }
  __syncthreads();
  for (int i = t; i < 2 * 2 * 4704; i += 256) {
    int wsel = i / 9408, rem = i % 9408, b = rem / 4704, j = rem % 4704;
    int o = j / 49, c2 = j % 49;
    const float* W = wsel ? wL : wR;
    unsigned p = 0;
    if (c2 < 48) {
      float w0 = W[o * 96 + 2 * c2] * scl[b][2 * c2];
      float w1 = W[o * 96 + 2 * c2 + 1] * scl[b][2 * c2 + 1];
      p = bfr(w0) | (bfr(w1) << 16);
    }
    (wsel ? w2L : w2R)[b * 4704 + j] = p;
  }
  for (int i = t; i < 2 * 2 * 96; i += 256) {
    int wsel = i / 192, rem = i % 192, b = rem / 96, o = rem % 96;
    const float* W = wsel ? wL : wR;
    float acc = (wsel ? bL : bR)[o];
    for (int c = 0; c < 96; ++c) acc += W[o * 96 + c] * sh[b][c];
    (wsel ? b2L : b2R)[b * 96 + o] = acc;
  }
}

// collapse IN1 replicas, compute BN1(IN) affine, pack w_l2 (unscaled)
__global__ __launch_bounds__(256) void prep_l2_k(const float* __restrict__ rawIN1,
    const float* __restrict__ w, const float* __restrict__ bi,
    const float* __restrict__ bn1w, const float* __restrict__ bn1b,
    unsigned* __restrict__ w2g, float* __restrict__ b2g,
    float* __restrict__ sclg, float* __restrict__ shfg) {
  __shared__ float st[384];
  int t = threadIdx.x;
  for (int i = t; i < 384; i += 256) {
    float s = 0.f;
    for (int r = 0; r < NREP; ++r) s += rawIN1[r * 384 + i];
    st[i] = s;
  }
  __syncthreads();
  if (t < 192) {
    int b = t / 96, c = t % 96;
    const float inv = 1.f / 96000.f;
    float m0 = st[c * 2] * inv, v0 = st[c * 2 + 1] * inv - m0 * m0;
    float m1 = st[192 + c * 2] * inv, v1 = st[192 + c * 2 + 1] * inv - m1 * m1;
    float bv = 0.5f * (v0 / (v0 + EPSV) + v1 / (v1 + EPSV));
    float bscale = rsqrtf(bv + EPSV) * bn1w[c];
    float mi = b ? m1 : m0, vi = b ? v1 : v0;
    float sc = rsqrtf(vi + EPSV) * bscale;
    sclg[t] = sc;
    shfg[t] = bn1b[c] - mi * sc;
    b2g[t] = bi[c];
  }
  for (int i = t; i < 4704; i += 256) {
    int o = i / 49, c2 = i % 49;
    unsigned p = 0;
    if (c2 < 48) p = bfr(w[o * 96 + 2 * c2]) | (bfr(w[o * 96 + 2 * c2 + 1]) << 16);
    w2g[i] = p;
  }
}

// =============== MFMA conv: D[o,nw] = W[96x96] @ X[96x96000] per batch ======
template <int MODE, int STATS>
__global__ __launch_bounds__(256) void convm_k(const float* __restrict__ xin,
    const unsigned* __restrict__ w2g, const float* __restrict__ b2g,
    const float* __restrict__ sclg, const float* __restrict__ shfg,
    float* __restrict__ outp, float* __restrict__ st_out) {
  __shared__ __align__(16) unsigned ldsW[96 * 49];
  __shared__ __align__(16) unsigned xt2[64 * 49];
  __shared__ float ldsB[96], lS[96], lH[96];
  __shared__ float ssum[4 * 96], sqsum[4 * 96];
  int tile = blockIdx.x % 1500, b = blockIdx.x / 1500;
  int nw0 = tile * 64;
  int t = threadIdx.x;
  const unsigned* wsrc = w2g + (MODE == 1 ? b * 4704 : 0);
  for (int i = t; i < 1176; i += 256)
    ((float4*)ldsW)[i] = ((const float4*)wsrc)[i];
  if (t < 96) {
    ldsB[t] = (MODE == 0) ? 0.f : b2g[b * 96 + t];
    if (MODE == 2) { lS[t] = sclg[b * 96 + t]; lH[t] = shfg[b * 96 + t]; }
  }
  __syncthreads();
  const float* xb = xin + b * CNW + nw0;
  for (int i = t; i < 768; i += 256) {
    int c2 = i >> 4, j4 = i & 15;
    const float* r0 = xb + (2 * c2) * 96000 + j4 * 4;
    float4 x0 = *(const float4*)r0;
    float4 x1 = *(const float4*)(r0 + 96000);
    if (MODE == 2) {
      float s0 = lS[2 * c2], h0 = lH[2 * c2];
      float s1 = lS[2 * c2 + 1], h1 = lH[2 * c2 + 1];
      x0.x = fmaxf(x0.x * s0 + h0, 0.f); x0.y = fmaxf(x0.y * s0 + h0, 0.f);
      x0.z = fmaxf(x0.z * s0 + h0, 0.f); x0.w = fmaxf(x0.w * s0 + h0, 0.f);
      x1.x = fmaxf(x1.x * s1 + h1, 0.f); x1.y = fmaxf(x1.y * s1 + h1, 0.f);
      x1.z = fmaxf(x1.z * s1 + h1, 0.f); x1.w = fmaxf(x1.w * s1 + h1, 0.f);
    }
    int base = j4 * 4;
    xt2[(base + 0) * 49 + c2] = bfr(x0.x) | (bfr(x1.x) << 16);
    xt2[(base + 1) * 49 + c2] = bfr(x0.y) | (bfr(x1.y) << 16);
    xt2[(base + 2) * 49 + c2] = bfr(x0.z) | (bfr(x1.z) << 16);
    xt2[(base + 3) * 49 + c2] = bfr(x0.w) | (bfr(x1.w) << 16);
  }
  __syncthreads();
  int lane = t & 63, nt = t >> 6;
  int l15 = lane & 15, kg = lane >> 4;
  f32x4 acc[6];
#pragma unroll
  for (int mt = 0; mt < 6; ++mt) acc[mt] = (f32x4){0.f, 0.f, 0.f, 0.f};
#pragma unroll
  for (int ks = 0; ks < 3; ++ks) {
    int cb = ks * 16 + kg * 4;
    FragU bf;
    int brow = (nt * 16 + l15) * 49 + cb;
    bf.u[0] = xt2[brow + 0]; bf.u[1] = xt2[brow + 1];
    bf.u[2] = xt2[brow + 2]; bf.u[3] = xt2[brow + 3];
#pragma unroll
    for (int mt = 0; mt < 6; ++mt) {
      FragU af;
      int arow = (mt * 16 + l15) * 49 + cb;
      af.u[0] = ldsW[arow + 0]; af.u[1] = ldsW[arow + 1];
      af.u[2] = ldsW[arow + 2]; af.u[3] = ldsW[arow + 3];
      acc[mt] = __builtin_amdgcn_mfma_f32_16x16x32_bf16(af.v, bf.v, acc[mt], 0, 0, 0);
    }
  }
  float* ob = outp + b * CNW + nw0 + nt * 16 + l15;
  float sv[6][4], qv[6][4];
#pragma unroll
  for (int mt = 0; mt < 6; ++mt)
#pragma unroll
    for (int r = 0; r < 4; ++r) {
      int o = mt * 16 + kg * 4 + r;
      float val = acc[mt][r] + ldsB[o];
      ob[o * 96000] = val;
      if (STATS) { sv[mt][r] = val; qv[mt][r] = val * val; }
    }
  if (STATS) {
#pragma unroll
    for (int msk = 1; msk <= 8; msk <<= 1)
#pragma unroll
      for (int mt = 0; mt < 6; ++mt)
#pragma unroll
        for (int r = 0; r < 4; ++r) {
          sv[mt][r] += __shfl_xor(sv[mt][r], msk, 64);
          qv[mt][r] += __shfl_xor(qv[mt][r], msk, 64);
        }
    if (l15 == 0)
#pragma unroll
      for (int mt = 0; mt < 6; ++mt)
#pragma unroll
        for (int r = 0; r < 4; ++r) {
          int o = mt * 16 + kg * 4 + r;
          ssum[nt * 96 + o] = sv[mt][r];
          sqsum[nt * 96 + o] = qv[mt][r];
        }
    __syncthreads();
    if (t < 96) {
      float S = ssum[t] + ssum[96 + t] + ssum[192 + t] + ssum[288 + t];
      float Q = sqsum[t] + sqsum[96 + t] + sqsum[192 + t] + sqsum[288 + t];
      float* dst = st_out + (tile & (NREP - 1)) * 384 + b * 192 + t * 2;
      atomicAdd(dst + 0, S);
      atomicAdd(dst + 1, Q);
    }
  }
}

// ---------------- collapse NREP replicas -> canonical [384] -----------------
__global__ __launch_bounds__(256) void collapse_k(const float* __restrict__ r0,
    float* __restrict__ o0, const float* __restrict__ r1, float* __restrict__ o1) {
  int t = blockIdx.x * 256 + threadIdx.x;
  const float* r = (t < 384) ? r0 : r1;
  float* o = (t < 384) ? o0 : o1;
  int i = (t < 384) ? t : t - 384;
  if (t < 768 && r) {
    float s = 0.f;
#pragma unroll
    for (int k = 0; k < NREP; ++k) s += r[k * 384 + i];
    o[i] = s;
  }
}

// ---------------- attention kernel A: block means -> sinkhorn -> top3 cut ---
__global__ __launch_bounds__(256) void attnA_k(const float* __restrict__ feat,
                                               float* __restrict__ Pg) {
  int head = blockIdx.x;
  int b = head / 576, rem = head % 576, c = rem / 6, gr = rem % 6;
  const float* fb = feat + b * CNW + c * 96000 + gr * 16;
  __shared__ float qm[160];
  __shared__ float L[110];
  int t = threadIdx.x;
  if (t < 160) {
    int m = t / 16, j = t % 16;
    float s = 0.f;
    for (int ss = 0; ss < 100; ++ss) s += fb[(m * 100 + ss) * 96 + j];
    qm[m * 16 + j] = s * 0.01f;
  }
  __syncthreads();
  if (t < 100) {
    int m = t / 10, n2 = t % 10;
    float acc = 0.f;
#pragma unroll
    for (int j = 0; j < 16; ++j) acc += qm[m * 16 + j] * qm[n2 * 16 + j];
    L[m * 11 + n2] = acc * ITEMP;
  }
  __syncthreads();
  for (int it = 0; it < 8; ++it) {
    if (t < 10) {
      float mx = -3.4e38f;
      for (int n2 = 0; n2 < 10; ++n2) mx = fmaxf(mx, L[t * 11 + n2]);
      float s = 0.f;
      for (int n2 = 0; n2 < 10; ++n2) s += expf(L[t * 11 + n2] - mx);
      float lse = mx + logf(s);
      for (int n2 = 0; n2 < 10; ++n2) L[t * 11 + n2] -= lse;
    }
    __syncthreads();
    if (t < 10) {
      float mx = -3.4e38f;
      for (int m = 0; m < 10; ++m) mx = fmaxf(mx, L[m * 11 + t]);
      float s = 0.f;
      for (int m = 0; m < 10; ++m) s += expf(L[m * 11 + t] - mx);
      float lse = mx + logf(s);
      for (int m = 0; m < 10; ++m) L[m * 11 + t] -= lse;
    }
    __syncthreads();
  }
  if (t < 10) {
    float p[10];
#pragma unroll
    for (int n2 = 0; n2 < 10; ++n2) p[n2] = expf(L[t * 11 + n2]);
    int i1 = -1, i2 = -1;
    float m1 = -1.f, m2 = -1.f, m3 = -1.f;
#pragma unroll
    for (int n2 = 0; n2 < 10; ++n2) if (p[n2] > m1) { m1 = p[n2]; i1 = n2; }
#pragma unroll
    for (int n2 = 0; n2 < 10; ++n2) if (n2 != i1 && p[n2] > m2) { m2 = p[n2]; i2 = n2; }
#pragma unroll
    for (int n2 = 0; n2 < 10; ++n2) if (n2 != i1 && n2 != i2 && p[n2] > m3) m3 = p[n2];
#pragma unroll
    for (int n2 = 0; n2 < 10; ++n2)
      Pg[head * 100 + t * 10 + n2] = (p[n2] >= m3) ? p[n2] : 0.f;
  }
}

// ---------------- attention kernel B — MFMA version -------------------------
// Per block (head, m): S = Q·K'^T and O = P·V' as bf16 MFMA GEMMs using the
// convm-verified fragment conventions (A [row][k-pairs], B [col][k-pairs],
// C/D col=lane&15 row=(lane>>4)*4+reg). 112-padded M/N, K 16->32 zero-pad.
// Full row-softmax via 4x shfl_xor within 16-lane groups; P repacked to bf16
// pairs via shfl_xor(1). 4 waves: w0-2 own 2 M-tiles, w3 owns 1.
__global__ __launch_bounds__(256) void attnB_k(const float* __restrict__ feat,
    const float* __restrict__ Pg, float* __restrict__ out) {
  __shared__ __align__(16) unsigned Qs[112 * 20];   // [row][d-pairs], pitch 20
  __shared__ __align__(16) unsigned Ks[112 * 20];   // [key][d-pairs]
  __shared__ __align__(16) unsigned Vt[16 * 68];    // [d][key-pairs], pitch 68
  __shared__ __align__(16) unsigned P2[112 * 68];   // [row][key-pairs]
  int m = blockIdx.x % 10;
  int head = blockIdx.x / 10;
  int b = head / 576, rem = head % 576, c = rem / 6, grp = rem % 6;
  const float* fb = feat + b * CNW + c * 96000 + grp * 16;
  int t = threadIdx.x;

  // zero pad regions (garbage bf16 could be inf/nan -> MFMA nan: zero it)
  for (int i = t; i < 896; i += 256) {          // Q,K d-pairs 8-15 (K 16->32)
    int row = i >> 3, cc = i & 7;
    Qs[row * 20 + 8 + cc] = 0;
    Ks[row * 20 + 8 + cc] = 0;
  }
  for (int i = t; i < 96; i += 256) {           // rows 100-111, d-pairs 0-7
    int row = 100 + (i >> 3), cc = i & 7;
    Qs[row * 20 + cc] = 0;
    Ks[row * 20 + cc] = 0;
  }
  for (int i = t; i < 224; i += 256) {          // V key-pairs 50-63 (keys>=100)
    int d = i / 14, cc = i % 14;
    Vt[d * 68 + 50 + cc] = 0;
  }
  for (int i = t; i < 896; i += 256) {          // P key-pairs 56-63 (keys>=112)
    int row = i >> 3, cc = i & 7;
    P2[row * 68 + 56 + cc] = 0;
  }

  float p[10];
#pragma unroll
  for (int n2 = 0; n2 < 10; ++n2) p[n2] = Pg[head * 100 + m * 10 + n2];

  // Q tile: unit (row s, quad q)
  for (int i4 = t; i4 < 400; i4 += 256) {
    int s = i4 >> 2, q = i4 & 3;
    float4 qv = *(const float4*)&fb[(m * 100 + s) * 96 + 4 * q];
    Qs[s * 20 + 2 * q]     = bfr(qv.x) | (bfr(qv.y) << 16);
    Qs[s * 20 + 2 * q + 1] = bfr(qv.z) | (bfr(qv.w) << 16);
  }
  // K',V' mix: unit (key-pair sp, quad q); v = elu(k) branchless
  if (t < 200) {
    int sp = t >> 2, q = t & 3;
    float4 ak0 = make_float4(0.f, 0.f, 0.f, 0.f), ak1 = ak0, av0 = ak0, av1 = ak0;
#pragma unroll
    for (int n2 = 0; n2 < 10; ++n2) {
      if (p[n2] != 0.f) {
        float pe = p[n2];
        float4 k0 = *(const float4*)&fb[(n2 * 100 + 2 * sp) * 96 + 4 * q];
        float4 k1 = *(const float4*)&fb[(n2 * 100 + 2 * sp + 1) * 96 + 4 * q];
        ak0.x += pe * k0.x; ak0.y += pe * k0.y; ak0.z += pe * k0.z; ak0.w += pe * k0.w;
        ak1.x += pe * k1.x; ak1.y += pe * k1.y; ak1.z += pe * k1.z; ak1.w += pe * k1.w;
        av0.x += pe * (fmaxf(k0.x, 0.f) + __expf(fminf(k0.x, 0.f)) - 1.f);
        av0.y += pe * (fmaxf(k0.y, 0.f) + __expf(fminf(k0.y, 0.f)) - 1.f);
        av0.z += pe * (fmaxf(k0.z, 0.f) + __expf(fminf(k0.z, 0.f)) - 1.f);
        av0.w += pe * (fmaxf(k0.w, 0.f) + __expf(fminf(k0.w, 0.f)) - 1.f);
        av1.x += pe * (fmaxf(k1.x, 0.f) + __expf(fminf(k1.x, 0.f)) - 1.f);
        av1.y += pe * (fmaxf(k1.y, 0.f) + __expf(fminf(k1.y, 0.f)) - 1.f);
        av1.z += pe * (fmaxf(k1.z, 0.f) + __expf(fminf(k1.z, 0.f)) - 1.f);
        av1.w += pe * (fmaxf(k1.w, 0.f) + __expf(fminf(k1.w, 0.f)) - 1.f);
      }
    }
    Ks[(2 * sp) * 20 + 2 * q]         = bfr(ak0.x) | (bfr(ak0.y) << 16);
    Ks[(2 * sp) * 20 + 2 * q + 1]     = bfr(ak0.z) | (bfr(ak0.w) << 16);
    Ks[(2 * sp + 1) * 20 + 2 * q]     = bfr(ak1.x) | (bfr(ak1.y) << 16);
    Ks[(2 * sp + 1) * 20 + 2 * q + 1] = bfr(ak1.z) | (bfr(ak1.w) << 16);
    Vt[(4 * q + 0) * 68 + sp] = bfr(av0.x) | (bfr(av1.x) << 16);
    Vt[(4 * q + 1) * 68 + sp] = bfr(av0.y) | (bfr(av1.y) << 16);
    Vt[(4 * q + 2) * 68 + sp] = bfr(av0.z) | (bfr(av1.z) << 16);
    Vt[(4 * q + 3) * 68 + sp] = bfr(av0.w) | (bfr(av1.w) << 16);
  }
  __syncthreads();

  int lane = t & 63, w = t >> 6;
  int l15 = lane & 15, kg = lane >> 4;
  int nmt = (w < 3) ? 2 : 1;
  float rinv[2][4];
#pragma unroll
  for (int im = 0; im < 2; ++im) {
    if (im < nmt) {
      int mt = w * 2 + im;
      FragU qf;
      int qbase = (mt * 16 + l15) * 20 + kg * 4;
      qf.u[0] = Qs[qbase + 0]; qf.u[1] = Qs[qbase + 1];
      qf.u[2] = Qs[qbase + 2]; qf.u[3] = Qs[qbase + 3];
      f32x4 s[7];
#pragma unroll
      for (int nt2 = 0; nt2 < 7; ++nt2) {
        FragU kf;
        int kbase = (nt2 * 16 + l15) * 20 + kg * 4;
        kf.u[0] = Ks[kbase + 0]; kf.u[1] = Ks[kbase + 1];
        kf.u[2] = Ks[kbase + 2]; kf.u[3] = Ks[kbase + 3];
        s[nt2] = __builtin_amdgcn_mfma_f32_16x16x32_bf16(
            qf.v, kf.v, (f32x4){0.f, 0.f, 0.f, 0.f}, 0, 0, 0);
      }
      // mask pad key-columns 100-111 (tile 6, col = 96 + l15)
      if (l15 >= 4) {
        s[6][0] = -3.0e38f; s[6][1] = -3.0e38f;
        s[6][2] = -3.0e38f; s[6][3] = -3.0e38f;
      }
#pragma unroll
      for (int r = 0; r < 4; ++r) {
        float mx = s[0][r];
#pragma unroll
        for (int nt2 = 1; nt2 < 7; ++nt2) mx = fmaxf(mx, s[nt2][r]);
        mx = fmaxf(mx, __shfl_xor(mx, 1, 64));
        mx = fmaxf(mx, __shfl_xor(mx, 2, 64));
        mx = fmaxf(mx, __shfl_xor(mx, 4, 64));
        mx = fmaxf(mx, __shfl_xor(mx, 8, 64));
        float pv[7];
        float sum = 0.f;
#pragma unroll
        for (int nt2 = 0; nt2 < 7; ++nt2) {
          pv[nt2] = __expf((s[nt2][r] - mx) * ITEMP);
          sum += pv[nt2];
        }
        sum += __shfl_xor(sum, 1, 64);
        sum += __shfl_xor(sum, 2, 64);
        sum += __shfl_xor(sum, 4, 64);
        sum += __shfl_xor(sum, 8, 64);
        rinv[im][r] = 1.f / sum;
        int row = mt * 16 + kg * 4 + r;
#pragma unroll
        for (int nt2 = 0; nt2 < 7; ++nt2) {
          float other = __shfl_xor(pv[nt2], 1, 64);
          if ((l15 & 1) == 0)
            P2[row * 68 + nt2 * 8 + (l15 >> 1)] = bfr(pv[nt2]) | (bfr(other) << 16);
        }
      }
    }
  }
  __syncthreads();
  // PV: O[row][d] = P2[row][keys] x V'[keys][d]
#pragma unroll
  for (int im = 0; im < 2; ++im) {
    if (im < nmt) {
      int mt = w * 2 + im;
      f32x4 acc = (f32x4){0.f, 0.f, 0.f, 0.f};
#pragma unroll
      for (int ks = 0; ks < 4; ++ks) {
        FragU pa, vb;
        int pbase = (mt * 16 + l15) * 68 + ks * 16 + kg * 4;
        pa.u[0] = P2[pbase + 0]; pa.u[1] = P2[pbase + 1];
        pa.u[2] = P2[pbase + 2]; pa.u[3] = P2[pbase + 3];
        int vbase = l15 * 68 + ks * 16 + kg * 4;
        vb.u[0] = Vt[vbase + 0]; vb.u[1] = Vt[vbase + 1];
        vb.u[2] = Vt[vbase + 2]; vb.u[3] = Vt[vbase + 3];
        acc = __builtin_amdgcn_mfma_f32_16x16x32_bf16(pa.v, vb.v, acc, 0, 0, 0);
      }
      float* obp = out + b * CNW + c * 96000 + grp * 16 + (m * 100) * 96 + l15;
#pragma unroll
      for (int r = 0; r < 4; ++r) {
        int row = mt * 16 + kg * 4 + r;
        if (row < 100) obp[row * 96] = acc[r] * rinv[im][r];
      }
    }
  }
}

// ------ t = swapaxes(feat_attn,1,3) + x, with fused GN stats ---------------
__global__ __launch_bounds__(256) void trans_add_k(const float* __restrict__ z,
    const float* __restrict__ x, float* __restrict__ out,
    float* __restrict__ rawGN) {
  __shared__ float ld[96 * 97];
  __shared__ float red[4 * 12];
  int b = blockIdx.x / 1000, n = blockIdx.x % 1000;
  int t = threadIdx.x;
  const float* zp = z + b * CNW + n * 96;
  for (int i = t; i < 9216; i += 256) {
    int r = i / 96, col = i % 96;
    ld[r * 97 + col] = zp[r * 96000 + col];
  }
  __syncthreads();
  const float* xp = x + b * CNW + n * 96;
  float* op = out + b * CNW + n * 96;
  float sg[6], qg[6];
#pragma unroll
  for (int g = 0; g < 6; ++g) { sg[g] = 0.f; qg[g] = 0.f; }
#pragma unroll
  for (int k = 0; k < 36; ++k) {
    int i = t + k * 256;
    int g = k / 6;                    // compile-time under unroll
    int cc = i / 96, ww = i % 96;
    float val = ld[ww * 97 + cc] + xp[cc * 96000 + ww];
    op[cc * 96000 + ww] = val;
    sg[g] += val;
    qg[g] += val * val;
  }
#pragma unroll
  for (int msk = 1; msk <= 32; msk <<= 1)
#pragma unroll
    for (int g = 0; g < 6; ++g) {
      sg[g] += __shfl_xor(sg[g], msk, 64);
      qg[g] += __shfl_xor(qg[g], msk, 64);
    }
  int wid = t >> 6;
  if ((t & 63) == 0)
#pragma unroll
    for (int g = 0; g < 6; ++g) {
      red[wid * 12 + g * 2 + 0] = sg[g];
      red[wid * 12 + g * 2 + 1] = qg[g];
    }
  __syncthreads();
  if (t < 12) {
    float s = red[t] + red[12 + t] + red[24 + t] + red[36 + t];
    atomicAdd(&rawGN[(n & (NREP - 1)) * 24 + b * 12 + t], s);
  }
}

// ---------------- out = relu( BN2(IN(l2)) + BNr(right_raw) ) -----------------
__global__ __launch_bounds__(256) void final_k(float* __restrict__ outp,
    const float* __restrict__ l2, const float* __restrict__ stR,
    const float* __restrict__ st2, const float* __restrict__ rw,
    const float* __restrict__ rb, const float* __restrict__ w2,
    const float* __restrict__ b2) {
  int stride = gridDim.x * 256;
  for (int i4 = blockIdx.x * 256 + threadIdx.x; i4 < 4608000; i4 += stride) {
    int i = i4 * 4;
    int b = i / CNW, o = (i / 96000) % 96;
    float mr = (stR[o * 2] + stR[192 + o * 2]) * (1.f / 192000.f);
    float vr = (stR[o * 2 + 1] + stR[192 + o * 2 + 1]) * (1.f / 192000.f) - mr * mr;
    float rs = rsqrtf(vr + EPSV) * rw[o];
    float rsh = rb[o] - mr * rs;
    const float inv = 1.f / 96000.f;
    float m0 = st2[o * 2] * inv,       v0 = st2[o * 2 + 1] * inv - m0 * m0;
    float m1 = st2[192 + o * 2] * inv, v1 = st2[192 + o * 2 + 1] * inv - m1 * m1;
    float bv = 0.5f * (v0 / (v0 + EPSV) + v1 / (v1 + EPSV));
    float ls = rsqrtf(bv + EPSV) * w2[o];
    float mi = b ? m1 : m0, vi = b ? v1 : v0;
    float lsc = rsqrtf(vi + EPSV) * ls;
    float lsh = b2[o] - mi * lsc;
    float4 R = ((float4*)outp)[i4];
    float4 L = ((const float4*)l2)[i4];
    float4 O;
    O.x = fmaxf(R.x * rs + rsh + L.x * lsc + lsh, 0.f);
    O.y = fmaxf(R.y * rs + rsh + L.y * lsc + lsh, 0.f);
    O.z = fmaxf(R.z * rs + rsh + L.z * lsc + lsh, 0.f);
    O.w = fmaxf(R.w * rs + rsh + L.w * lsc + lsh, 0.f);
    ((float4*)outp)[i4] = O;
  }
}

extern "C" void kernel_launch(void* const* d_in, const int* in_sizes, int n_in,
                              void* d_out, int out_size, void* d_ws, size_t ws_size,
                              hipStream_t stream) {
  const float* x        = (const float*)d_in[0];
  const float* w_linear = (const float*)d_in[1];
  const float* gn_w     = (const float*)d_in[2];
  const float* gn_b     = (const float*)d_in[3];
  const float* w_right  = (const float*)d_in[4];
  const float* b_right  = (const float*)d_in[5];
  const float* bn_r_w   = (const float*)d_in[6];
  const float* bn_r_b   = (const float*)d_in[7];
  const float* w_l1     = (const float*)d_in[8];
  const float* b_l1     = (const float*)d_in[9];
  const float* bn1_w    = (const float*)d_in[10];
  const float* bn1_b    = (const float*)d_in[11];
  const float* w_l2     = (const float*)d_in[12];
  const float* b_l2     = (const float*)d_in[13];
  const float* bn2_w    = (const float*)d_in[14];
  const float* bn2_b    = (const float*)d_in[15];
  float* out = (float*)d_out;

  float* A      = (float*)d_ws;            // TOT
  float* Bb     = A + TOT;                 // TOT
  float* Pg     = Bb + TOT;                // 115200
  float* rawGN  = Pg + 115200;             // NREP*24 = 384
  float* rawBNr = rawGN + NREP * 24;       // NREP*384
  float* rawIN1 = rawBNr + NREP * 384;     // NREP*384
  float* rawIN2 = rawIN1 + NREP * 384;     // NREP*384
  float* stBNr  = rawIN2 + NREP * 384;     // 384
  float* stIN2  = stBNr + 384;             // 384
  unsigned* w2_0  = (unsigned*)(stIN2 + 384);  // 4704
  unsigned* w2R   = w2_0 + 4704;               // 2*4704
  unsigned* w2L   = w2R + 2 * 4704;            // 2*4704
  unsigned* w2l2  = w2L + 2 * 4704;            // 4704
  float* b2R   = (float*)(w2l2 + 4704);        // 192
  float* b2L   = b2R + 192;                    // 192
  float* b2l2  = b2L + 192;                    // 192
  float* scl1g = b2l2 + 192;                   // 192
  float* shf1g = scl1g + 192;                  // 192

  hipMemsetAsync(rawGN, 0, (NREP * 24 + 3 * NREP * 384) * sizeof(float), stream);

  prep0_k<<<1, 256, 0, stream>>>(w_linear, w2_0);
  // feat = conv1x1(x, w_linear) -> A   [fp32: protects the sinkhorn top-3 cut]
  conv_k<<<2000, 256, 0, stream>>>(x, w_linear, A);
  attnA_k<<<1152, 256, 0, stream>>>(A, Pg);
  attnB_k<<<11520, 256, 0, stream>>>(A, Pg, Bb);
  trans_add_k<<<2000, 256, 0, stream>>>(Bb, x, A, rawGN);
  prep_rl_k<<<1, 256, 0, stream>>>(rawGN, w_right, b_right, w_l1, b_l1,
                                   gn_w, gn_b, w2R, b2R, w2L, b2L);
  convm_k<1, 1><<<3000, 256, 0, stream>>>(A, w2R, b2R, nullptr, nullptr,
                                          out, rawBNr);
  convm_k<1, 1><<<3000, 256, 0, stream>>>(A, w2L, b2L, nullptr, nullptr,
                                          Bb, rawIN1);
  prep_l2_k<<<1, 256, 0, stream>>>(rawIN1, w_l2, b_l2, bn1_w, bn1_b,
                                   w2l2, b2l2, scl1g, shf1g);
  convm_k<2, 1><<<3000, 256, 0, stream>>>(Bb, w2l2, b2l2, scl1g, shf1g,
                                          A, rawIN2);
  collapse_k<<<3, 256, 0, stream>>>(rawBNr, stBNr, rawIN2, stIN2);
  final_k<<<2048, 256, 0, stream>>>(out, A, stBNr, stIN2,
                                    bn_r_w, bn_r_b, bn2_w, bn2_b);
}